// Round 5
// baseline (945.320 us; speedup 1.0000x reference)
//
#include <hip/hip_runtime.h>

// B=2, S=2048, D=1024, H=16, d_k=64, WINDOW=256
// d_out = out [B,S,D] fp32  ++  attn [B,H,S,S] fp32
// ws (112 MB): Xs bf16 3x[4096x2048] | XsAO bf16 [4096x2048] | Wt bf16 4x[1024x2048]
//              | Qb,Kb,Vb bf16 [4096x1024] | Vt bf16 [B,H,64,2048]
//
// v7: gemm_qkv zero-drip now rides ACROSS the K-loop barriers via counted
// s_waitcnt vmcnt(2) (T4): the 2 NT stores are the youngest vmem ops, the 4
// global_load_lds staging loads are the oldest -> vmcnt(2) completes staging
// without draining stores (v6 drained vmcnt(0) -> drip serialized).
// attn: XCD-contiguous swizzle (L2 K/V locality) + bf16 probs overlaid in P.

constexpr int Bb = 2, Ss = 2048, Dd = 1024, Hh = 16, WINw = 256;
constexpr size_t XS_SLAB = (size_t)4096 * 2048;  // bf16 elems
constexpr size_t WT_SLAB = (size_t)1024 * 2048;  // bf16 elems
constexpr size_t QB_SLAB = (size_t)4096 * 1024;  // bf16 elems
constexpr size_t ATTN_BYTES = (size_t)Bb * Hh * Ss * Ss * 4;  // 512 MiB

typedef short s16x8 __attribute__((ext_vector_type(8)));
typedef float f32x4 __attribute__((ext_vector_type(4)));

typedef __attribute__((address_space(3))) unsigned int lds_uint;
typedef const __attribute__((address_space(1))) unsigned int gbl_uint;

// async global->LDS, 16B per lane; LDS dest = wave-uniform base + lane*16
__device__ __forceinline__ void gld_lds16(const void* g, void* l) {
  __builtin_amdgcn_global_load_lds((gbl_uint*)g, (lds_uint*)l, 16, 0, 0);
}

// LDS-only drain + barrier (lets global stores keep draining across it)
__device__ __forceinline__ void lgkm_barrier() {
  asm volatile("s_waitcnt lgkmcnt(0)" ::: "memory");
  __builtin_amdgcn_s_barrier();
}

__device__ inline unsigned short f2bf(float x) {
  unsigned u = __float_as_uint(x);
  u += 0x7fff + ((u >> 16) & 1);  // RNE
  return (unsigned short)(u >> 16);
}
__device__ inline float bf2f(unsigned short h) {
  return __uint_as_float(((unsigned)h) << 16);
}

// ---------------------------------------------------------------------------
// Merged conversions (single dispatch).
// id < 12288 : convert_x — fp32 [4096x1024] -> bf16 split [4096x2048]=[hi|lo]
// id >= 12288: convert_w — W [1024x1024] fp32 -> Wt bf16 [n][2048]=[Whi^T|Wlo^T]
// ---------------------------------------------------------------------------
__global__ __launch_bounds__(256) void convert_xw(
    const float* __restrict__ x0, const float* __restrict__ x1,
    const float* __restrict__ x2, unsigned short* __restrict__ Xs,
    const float* __restrict__ w0, const float* __restrict__ w1,
    const float* __restrict__ w2, const float* __restrict__ w3,
    unsigned short* __restrict__ Wt) {
  __shared__ float T[64][65];
  const int id = blockIdx.x;
  const int t = threadIdx.x;
  if (id < 12288) {
    int z = id >> 12;
    int bx = id & 4095;
    const float* src = z == 0 ? x0 : (z == 1 ? x1 : x2);
    unsigned short* dst = Xs + (size_t)z * XS_SLAB;
    size_t idx = ((size_t)bx * 256 + t) * 4;
    int r = (int)(idx >> 10);
    int c = (int)(idx & 1023);
    f32x4 v = *(const f32x4*)&src[idx];
    unsigned short hi[4], lo[4];
#pragma unroll
    for (int i = 0; i < 4; ++i) {
      float vi = v[i];
      hi[i] = f2bf(vi);
      lo[i] = f2bf(vi - bf2f(hi[i]));
    }
    ushort4 h4 = {hi[0], hi[1], hi[2], hi[3]};
    ushort4 l4 = {lo[0], lo[1], lo[2], lo[3]};
    *(ushort4*)&dst[(size_t)r * 2048 + c] = h4;
    *(ushort4*)&dst[(size_t)r * 2048 + 1024 + c] = l4;
  } else {
    int wid = id - 12288;
    int z = wid >> 8;
    int by = (wid >> 4) & 15;
    int bx = wid & 15;
    const float* W = z == 0 ? w0 : (z == 1 ? w1 : (z == 2 ? w2 : w3));
    unsigned short* dst = Wt + (size_t)z * WT_SLAB;
    int k0 = by * 64, n0 = bx * 64;
#pragma unroll
    for (int i = 0; i < 4; ++i) {
      int row = (t >> 4) + i * 16;
      int c4 = (t & 15) * 4;
      f32x4 v = *(const f32x4*)&W[(size_t)(k0 + row) * 1024 + n0 + c4];
      T[row][c4 + 0] = v[0]; T[row][c4 + 1] = v[1];
      T[row][c4 + 2] = v[2]; T[row][c4 + 3] = v[3];
    }
    __syncthreads();
    int n = t >> 2;
    int kc = (t & 3) * 16;
    unsigned short hi[16], lo[16];
#pragma unroll
    for (int j = 0; j < 16; ++j) {
      float x = T[kc + j][n];
      hi[j] = f2bf(x);
      lo[j] = f2bf(x - bf2f(hi[j]));
    }
    size_t base = (size_t)(n0 + n) * 2048 + k0 + kc;
#pragma unroll
    for (int j4 = 0; j4 < 4; ++j4) {
      ushort4 h4 = {hi[j4 * 4], hi[j4 * 4 + 1], hi[j4 * 4 + 2], hi[j4 * 4 + 3]};
      ushort4 l4 = {lo[j4 * 4], lo[j4 * 4 + 1], lo[j4 * 4 + 2], lo[j4 * 4 + 3]};
      *(ushort4*)&dst[base + j4 * 4] = h4;
      *(ushort4*)&dst[base + 1024 + j4 * 4] = l4;
    }
  }
}

// ---------------------------------------------------------------------------
// QKV GEMM: C[4096x1024] = A[4096x3072] @ W[3072x1024] + bias (bf16x3 split).
// 128x128 tile, global_load_lds double-buffer, XCD-swizzled block map.
// Drip-writes the full 512MB attn zero region. Barrier = s_waitcnt vmcnt(2)
// (staging loads are the oldest 4 vmem ops; the 2 drip stores are youngest
// and ride across the barrier — m135 oldest-first vmcnt semantics).
// ---------------------------------------------------------------------------
__global__ __launch_bounds__(256, 3) void gemm_qkv(
    const unsigned short* __restrict__ Abase,
    const unsigned short* __restrict__ Wtbase,
    unsigned short* __restrict__ Cbase, const float* __restrict__ bb0,
    const float* __restrict__ bb1, const float* __restrict__ bb2,
    float* __restrict__ attnz) {
  __shared__ s16x8 As[2][512];
  __shared__ s16x8 Bs[2][512];
  int z = blockIdx.z;
  const unsigned short* A = Abase + (size_t)z * XS_SLAB;
  const unsigned short* Wt = Wtbase + (size_t)z * WT_SLAB;
  const float* bias = z == 0 ? bb0 : (z == 1 ? bb1 : bb2);
  const float scl = (z == 0) ? 0.125f : 1.0f;

  const int t = threadIdx.x;
  const int lane = t & 63, wave = t >> 6;
  const int wm = wave & 1, wn = wave >> 1;

  // XCD swizzle: flat = bn-fast id; XCD c gets bm in [4c, 4c+4) x all bn.
  const int flat = blockIdx.x + (blockIdx.y << 3);          // 0..255
  const int swz = (flat & 7) * 32 + (flat >> 3);
  const int bm = (swz >> 3) * 128, bn = (swz & 7) * 128;

  // attn-zero drip state: contiguous 192KB chunk per wave
  const int flat3 = flat + (z << 8);                        // 0..767
  const size_t zbase = (size_t)(flat3 * 4 + wave) * 196608;
  char* const az = (char*)attnz;
  const f32x4 zv = {0.f, 0.f, 0.f, 0.f};

  f32x4 acc[4][4] = {};

  const int s0 = t, s1 = t + 256;
  const int r0 = s0 >> 2, c0 = (s0 & 3) ^ ((r0 >> 1) & 3);
  const int r1 = s1 >> 2, c1 = (s1 & 3) ^ ((r1 >> 1) & 3);
  const unsigned short* A0 = A + (size_t)(bm + r0) * 2048 + c0 * 8;
  const unsigned short* A1 = A + (size_t)(bm + r1) * 2048 + c1 * 8;
  const unsigned short* B0 = Wt + (size_t)(bn + r0) * 2048 + c0 * 8;
  const unsigned short* B1 = Wt + (size_t)(bn + r1) * 2048 + c1 * 8;

  const int m15 = lane & 15, q = lane >> 4;

  gld_lds16(A0, &As[0][wave * 64]);
  gld_lds16(A1, &As[0][256 + wave * 64]);
  gld_lds16(B0, &Bs[0][wave * 64]);
  gld_lds16(B1, &Bs[0][256 + wave * 64]);
  __syncthreads();

  int cur = 0;
  for (int kb = 0; kb < 3072; kb += 32) {
    const int kn = kb + 32;
    const bool more = (kn < 3072);
    if (more) {
      // segments: A_hi*W_hi | A_hi*W_lo | A_lo*W_hi
      int asrc = kn < 1024 ? kn : kn - 1024;
      int wsrc = kn < 2048 ? kn : kn - 2048;
      gld_lds16(A0 + asrc, &As[cur ^ 1][wave * 64]);
      gld_lds16(A1 + asrc, &As[cur ^ 1][256 + wave * 64]);
      gld_lds16(B0 + wsrc, &Bs[cur ^ 1][wave * 64]);
      gld_lds16(B1 + wsrc, &Bs[cur ^ 1][256 + wave * 64]);
    }
    // keep issue order: staging loads (oldest) before drip stores (youngest)
    __builtin_amdgcn_sched_barrier(0);

    // attn-zero drip: ALWAYS exactly 2 NT stores/wave (clamped tail) so the
    // vmcnt(2) barrier count below is exact for every wave.
    {
      size_t off0 = zbase + (size_t)(kb >> 5) * 2048 + (size_t)(lane << 4);
      size_t off1 = off0 + 1024;
      if (off0 >= ATTN_BYTES) off0 = ATTN_BYTES - 16;
      if (off1 >= ATTN_BYTES) off1 = ATTN_BYTES - 16;
      __builtin_nontemporal_store(zv, (f32x4*)(az + off0));
      __builtin_nontemporal_store(zv, (f32x4*)(az + off1));
    }

    s16x8 af[4], bf[4];
#pragma unroll
    for (int mt = 0; mt < 4; ++mt) {
      int r = wm * 64 + mt * 16 + m15;
      af[mt] = As[cur][r * 4 + (q ^ ((r >> 1) & 3))];
    }
#pragma unroll
    for (int nt = 0; nt < 4; ++nt) {
      int r = wn * 64 + nt * 16 + m15;
      bf[nt] = Bs[cur][r * 4 + (q ^ ((r >> 1) & 3))];
    }
#pragma unroll
    for (int mt = 0; mt < 4; ++mt)
#pragma unroll
      for (int nt = 0; nt < 4; ++nt)
        acc[mt][nt] = __builtin_amdgcn_mfma_f32_16x16x32_bf16(
            af[mt], bf[nt], acc[mt][nt], 0, 0, 0);

    if (more) {
      // counted barrier: all but the 2 youngest vmem ops (the drip stores)
      // must be complete -> the 4 staging loads are done; stores float.
      asm volatile("s_waitcnt vmcnt(2) lgkmcnt(0)" ::: "memory");
      __builtin_amdgcn_s_barrier();
      cur ^= 1;
    }
  }

#pragma unroll
  for (int nt = 0; nt < 4; ++nt) {
    int col = bn + wn * 64 + nt * 16 + m15;
    float bv = bias[col];
#pragma unroll
    for (int mt = 0; mt < 4; ++mt) {
      int rowb = bm + wm * 64 + mt * 16 + q * 4;
#pragma unroll
      for (int i = 0; i < 4; ++i) {
        float val = (acc[mt][nt][i] + bv) * scl;
        (Cbase + (size_t)z * QB_SLAB)[(size_t)(rowb + i) * 1024 + col] =
            f2bf(val);
      }
    }
  }
}

// ---------------------------------------------------------------------------
// Out-projection GEMM: 64x128 tile, 512 blocks = 2/CU. XCD-swizzled.
// ---------------------------------------------------------------------------
__global__ __launch_bounds__(256, 2) void gemm_out(
    const unsigned short* __restrict__ A,   // XsAO [4096][2048]
    const unsigned short* __restrict__ Wt,  // Wo^T split [1024][2048]
    float* __restrict__ C, const float* __restrict__ bias) {
  __shared__ s16x8 As[2][256];
  __shared__ s16x8 Bs[2][512];
  const int t = threadIdx.x;
  const int lane = t & 63, wave = t >> 6;
  const int wm = wave & 1, wn = wave >> 1;

  const int flat = blockIdx.x + (blockIdx.y << 3);          // 0..511
  const int swz = (flat & 7) * 64 + (flat >> 3);
  const int bm = (swz >> 3) * 64, bn = (swz & 7) * 128;

  f32x4 acc[2][4] = {};

  const int ra = t >> 2, ca = (t & 3) ^ ((ra >> 1) & 3);
  const int s0 = t, s1 = t + 256;
  const int r0 = s0 >> 2, c0 = (s0 & 3) ^ ((r0 >> 1) & 3);
  const int r1 = s1 >> 2, c1 = (s1 & 3) ^ ((r1 >> 1) & 3);
  const unsigned short* Ap = A + (size_t)(bm + ra) * 2048 + ca * 8;
  const unsigned short* B0 = Wt + (size_t)(bn + r0) * 2048 + c0 * 8;
  const unsigned short* B1 = Wt + (size_t)(bn + r1) * 2048 + c1 * 8;

  const int m15 = lane & 15, q = lane >> 4;

  gld_lds16(Ap, &As[0][wave * 64]);
  gld_lds16(B0, &Bs[0][wave * 64]);
  gld_lds16(B1, &Bs[0][256 + wave * 64]);
  __syncthreads();

  int cur = 0;
  for (int kb = 0; kb < 3072; kb += 32) {
    const int kn = kb + 32;
    if (kn < 3072) {
      int asrc = kn < 1024 ? kn : kn - 1024;
      int wsrc = kn < 2048 ? kn : kn - 2048;
      gld_lds16(Ap + asrc, &As[cur ^ 1][wave * 64]);
      gld_lds16(B0 + wsrc, &Bs[cur ^ 1][wave * 64]);
      gld_lds16(B1 + wsrc, &Bs[cur ^ 1][256 + wave * 64]);
    }

    s16x8 af[2], bf[4];
#pragma unroll
    for (int mt = 0; mt < 2; ++mt) {
      int r = wm * 32 + mt * 16 + m15;
      af[mt] = As[cur][r * 4 + (q ^ ((r >> 1) & 3))];
    }
#pragma unroll
    for (int nt = 0; nt < 4; ++nt) {
      int r = wn * 64 + nt * 16 + m15;
      bf[nt] = Bs[cur][r * 4 + (q ^ ((r >> 1) & 3))];
    }
#pragma unroll
    for (int mt = 0; mt < 2; ++mt)
#pragma unroll
      for (int nt = 0; nt < 4; ++nt)
        acc[mt][nt] = __builtin_amdgcn_mfma_f32_16x16x32_bf16(
            af[mt], bf[nt], acc[mt][nt], 0, 0, 0);

    if (kn < 3072) {
      __syncthreads();
      cur ^= 1;
    }
  }

#pragma unroll
  for (int nt = 0; nt < 4; ++nt) {
    int col = bn + wn * 64 + nt * 16 + m15;
    float bv = bias[col];
#pragma unroll
    for (int mt = 0; mt < 2; ++mt) {
      int rowb = bm + wm * 32 + mt * 16 + q * 4;
#pragma unroll
      for (int i = 0; i < 4; ++i) {
        __builtin_nontemporal_store(
            acc[mt][nt][i] + bv, &C[(size_t)(rowb + i) * 1024 + col]);
      }
    }
  }
}

// ---------------------------------------------------------------------------
// Vb [4096][1024] bf16 -> Vt [b][h][d][s] bf16 (per-head transposed).
// ---------------------------------------------------------------------------
__global__ __launch_bounds__(256) void transpose_v(
    const unsigned short* __restrict__ Vb, unsigned short* __restrict__ Vt) {
  __shared__ unsigned short T[64][88];
  const int b = blockIdx.z, h = blockIdx.y, s0 = blockIdx.x * 64;
  const int t = threadIdx.x;
  {
    int row = t >> 2, part = t & 3;
    const unsigned short* src =
        Vb + (size_t)(b * Ss + s0 + row) * 1024 + h * 64 + part * 16;
    s16x8 v0 = *(const s16x8*)src;
    s16x8 v1 = *(const s16x8*)(src + 8);
    *(s16x8*)&T[row][part * 16] = v0;
    *(s16x8*)&T[row][part * 16 + 8] = v1;
  }
  __syncthreads();
  {
    int d = t & 63, sw = t >> 6;
    unsigned short tmp[16];
#pragma unroll
    for (int i = 0; i < 16; ++i) tmp[i] = T[sw * 16 + i][d];
    unsigned short* dst =
        Vt + ((size_t)((b * Hh + h) * 64 + d)) * 2048 + s0 + sw * 16;
    *(s16x8*)dst = *(const s16x8*)&tmp[0];
    *(s16x8*)(dst + 8) = *(const s16x8*)&tmp[8];
  }
}

// ---------------------------------------------------------------------------
// Fused attention v6: per block = one (b,h) x 16-query tile, 4 waves.
// XCD-contiguous swizzle: XCD x owns logical tiles [x*512,(x+1)*512) = 4 full
// (b,h) panels -> concurrent K/V L2 footprint ~512KB/XCD (no thrash).
// S1: scores (fp32) via MFMA -> LDS P.  S2: softmax; band-only global write
// from regs; probs stored bf16 OVERLAID on P row (row fully consumed first).
// S3: PV reads bf16 probs directly (no f2bf chain).
// ---------------------------------------------------------------------------
constexpr int SW3 = 556;  // f32 stride: 556%32=12 -> <=2-way banks; 16B-aligned
__global__ __launch_bounds__(256) void attn_v6(
    const unsigned short* __restrict__ Qb, const unsigned short* __restrict__ Kb,
    const unsigned short* __restrict__ Vt, float* __restrict__ attn,
    unsigned short* __restrict__ XsAO) {
  __shared__ float P[16 * SW3];  // 35.6 KB
  const int t = threadIdx.x;
  const int lane = t & 63, wave = t >> 6;
  const int m15 = lane & 15, quad = lane >> 4;
  const int bid0 = blockIdx.x;
  const int bid = (bid0 & 7) * 512 + (bid0 >> 3);  // XCD-contiguous (4096=8*512)
  const int qt = bid & 127, h = (bid >> 7) & 15, b = bid >> 11;
  const int q0 = qt * 16;
  int jlo = q0 - WINw; if (jlo < 0) jlo = 0;
  int jhi = q0 + 15 + WINw; if (jhi > Ss - 1) jhi = Ss - 1;
  const int ncols = jhi - jlo + 1;  // multiple of 16, <=528
  const int ntiles = ncols >> 4;

  // ---- stage 1: scores via MFMA -> P (fp32) ----
  {
    const unsigned short* qrow =
        Qb + (size_t)(b * Ss + q0 + m15) * 1024 + h * 64 + quad * 8;
    s16x8 aq0 = *(const s16x8*)qrow;
    s16x8 aq1 = *(const s16x8*)(qrow + 32);
    for (int nt = wave; nt < ntiles; nt += 4) {
      const unsigned short* krow =
          Kb + (size_t)(b * Ss + jlo + nt * 16 + m15) * 1024 + h * 64 + quad * 8;
      s16x8 b0 = *(const s16x8*)krow;
      s16x8 b1 = *(const s16x8*)(krow + 32);
      f32x4 c = {0.f, 0.f, 0.f, 0.f};
      __builtin_amdgcn_s_setprio(1);
      c = __builtin_amdgcn_mfma_f32_16x16x32_bf16(aq0, b0, c, 0, 0, 0);
      c = __builtin_amdgcn_mfma_f32_16x16x32_bf16(aq1, b1, c, 0, 0, 0);
      __builtin_amdgcn_s_setprio(0);
      float* pp = &P[(quad * 4) * SW3 + nt * 16 + m15];
#pragma unroll
      for (int i = 0; i < 4; ++i) pp[i * SW3] = c[i];
    }
  }
  lgkm_barrier();

  // ---- stage 2: softmax; band global write; bf16 probs overlay into P ----
  {
#pragma unroll
    for (int ri = 0; ri < 4; ++ri) {
      const int r = wave * 4 + ri;
      const int qq = q0 + r;
      int lo = qq - WINw; if (lo < 0) lo = 0;
      int hi = qq + WINw; if (hi > Ss - 1) hi = Ss - 1;
      const int clo = lo - jlo, chi = hi - jlo;
      float sv[9];
      bool ib[9];
      float m = -1e30f;
#pragma unroll
      for (int k2 = 0; k2 < 9; ++k2) {
        int c = k2 * 64 + lane;
        bool inb = (c >= clo) && (c <= chi);
        ib[k2] = inb;
        float vv = inb ? P[r * SW3 + c] : -1e30f;
        sv[k2] = vv;
        m = fmaxf(m, vv);
      }
#pragma unroll
      for (int off = 32; off; off >>= 1) m = fmaxf(m, __shfl_xor(m, off, 64));
      float e[9], l = 0.f;
#pragma unroll
      for (int k2 = 0; k2 < 9; ++k2) { e[k2] = __expf(sv[k2] - m); l += e[k2]; }
#pragma unroll
      for (int off = 32; off; off >>= 1) l += __shfl_xor(l, off, 64);
      const float inv = 1.f / l;
      // overlay: row r's fp32 scores fully consumed into sv[] above
      unsigned short* pb = (unsigned short*)&P[r * SW3];
      float* arow = attn + ((size_t)((b * Hh + h) * Ss + qq)) * Ss + jlo;
#pragma unroll
      for (int k2 = 0; k2 < 9; ++k2) {
        int c = k2 * 64 + lane;
        float w = ib[k2] ? e[k2] * inv : 0.f;
        if (c < 544) pb[c] = f2bf(w);
        if (c < ncols) __builtin_nontemporal_store(w, &arow[c]);
      }
    }
  }
  lgkm_barrier();

  // ---- stage 3: PV via MFMA; wave = d-tile; A-frags read bf16 from P ----
  {
    const int ntk = (ncols + 31) >> 5;
    const unsigned short* vtrow =
        Vt + ((size_t)((b * Hh + h) * 64 + wave * 16 + m15)) * 2048 + jlo +
        quad * 8;
    f32x4 o = {0.f, 0.f, 0.f, 0.f};
    const unsigned short* pbrow = (const unsigned short*)&P[m15 * SW3];
    for (int ks = 0; ks < ntk; ++ks) {
      s16x8 af = *(const s16x8*)&pbrow[ks * 32 + quad * 8];
      s16x8 bf = *(const s16x8*)(vtrow + ks * 32);
      __builtin_amdgcn_s_setprio(1);
      o = __builtin_amdgcn_mfma_f32_16x16x32_bf16(af, bf, o, 0, 0, 0);
      __builtin_amdgcn_s_setprio(0);
    }
    const int dcol = h * 64 + wave * 16 + m15;
#pragma unroll
    for (int i = 0; i < 4; ++i) {
      int row = q0 + quad * 4 + i;
      unsigned short hi = f2bf(o[i]);
      unsigned short lo = f2bf(o[i] - bf2f(hi));
      unsigned short* dst = XsAO + (size_t)(b * Ss + row) * 2048 + dcol;
      dst[0] = hi;
      dst[1024] = lo;
    }
  }
}

// ---------------------------------------------------------------------------
extern "C" void kernel_launch(void* const* d_in, const int* in_sizes, int n_in,
                              void* d_out, int out_size, void* d_ws,
                              size_t ws_size, hipStream_t stream) {
  const float* q  = (const float*)d_in[0];
  const float* k  = (const float*)d_in[1];
  const float* v  = (const float*)d_in[2];
  const float* Wq = (const float*)d_in[3];
  const float* bq = (const float*)d_in[4];
  const float* Wk = (const float*)d_in[5];
  const float* bk = (const float*)d_in[6];
  const float* Wv = (const float*)d_in[7];
  const float* bv = (const float*)d_in[8];
  const float* Wo = (const float*)d_in[9];
  const float* bo = (const float*)d_in[10];

  float* out = (float*)d_out;
  float* attn = out + (size_t)Bb * Ss * Dd;

  unsigned short* Xs   = (unsigned short*)d_ws;   // 48 MB
  unsigned short* XsAO = Xs + 3 * XS_SLAB;        // 16 MB
  unsigned short* Wt   = XsAO + XS_SLAB;          // 16 MB
  unsigned short* Qb   = Wt + 4 * WT_SLAB;        // 8 MB
  unsigned short* Kb   = Qb + QB_SLAB;            // 8 MB
  unsigned short* Vb   = Kb + QB_SLAB;            // 8 MB
  unsigned short* Vt   = Vb + QB_SLAB;            // 8 MB (+slack after)

  hipLaunchKernelGGL(convert_xw, dim3(12288 + 1024), dim3(256), 0, stream,
                     q, k, v, Xs, Wq, Wk, Wv, Wo, Wt);
  hipLaunchKernelGGL(gemm_qkv, dim3(8, 32, 3), dim3(256), 0, stream,
                     Xs, Wt, Qb, bq, bk, bv, attn);
  hipLaunchKernelGGL(transpose_v, dim3(32, 16, 2), dim3(256), 0, stream,
                     Vb, Vt);
  hipLaunchKernelGGL(attn_v6, dim3(Bb * Hh * (Ss / 16)), dim3(256), 0, stream,
                     Qb, Kb, Vt, attn, XsAO);
  hipLaunchKernelGGL(gemm_out, dim3(8, 64, 1), dim3(256), 0, stream,
                     XsAO, Wt + 3 * WT_SLAB, out, bo);
}

// Round 6
// 782.247 us; speedup vs baseline: 1.2085x; 1.2085x over previous
//
#include <hip/hip_runtime.h>

// B=2, S=2048, D=1024, H=16, d_k=64, WINDOW=256
// d_out = out [B,S,D] fp32  ++  attn [B,H,S,S] fp32
// ws (112 MB): Xs bf16 3x[4096x2048] | XsAO bf16 [4096x2048] | Wt bf16 4x[1024x2048]
//              | Qb,Kb,Vb bf16 [4096x1024] | Vt bf16 [B,H,64,2048]
//
// v8: drip-zeroing of the 512MB attn out-of-band region rides inside
// gemm_qkv with BATCHED stores: 16 NT stores (16KB/wave) every 8th K-step,
// issued at the TOP of the body (right after the previous barrier) so they
// have the whole body + 11 co-resident waves to complete before the next
// vmcnt(0) drain. No inline asm, no sched_barrier (v7's m141-style mistakes),
// no clamped hot-line stores (guarded, wave-uniform skip).

constexpr int Bb = 2, Ss = 2048, Dd = 1024, Hh = 16, WINw = 256;
constexpr size_t XS_SLAB = (size_t)4096 * 2048;  // bf16 elems
constexpr size_t WT_SLAB = (size_t)1024 * 2048;  // bf16 elems
constexpr size_t QB_SLAB = (size_t)4096 * 1024;  // bf16 elems
constexpr size_t ATTN_BYTES = (size_t)Bb * Hh * Ss * Ss * 4;  // 512 MiB

typedef short s16x8 __attribute__((ext_vector_type(8)));
typedef float f32x4 __attribute__((ext_vector_type(4)));

typedef __attribute__((address_space(3))) unsigned int lds_uint;
typedef const __attribute__((address_space(1))) unsigned int gbl_uint;

// async global->LDS, 16B per lane; LDS dest = wave-uniform base + lane*16
__device__ __forceinline__ void gld_lds16(const void* g, void* l) {
  __builtin_amdgcn_global_load_lds((gbl_uint*)g, (lds_uint*)l, 16, 0, 0);
}

// LDS-only drain + barrier (lets global stores keep draining across it)
__device__ __forceinline__ void lgkm_barrier() {
  asm volatile("s_waitcnt lgkmcnt(0)" ::: "memory");
  __builtin_amdgcn_s_barrier();
}

__device__ inline unsigned short f2bf(float x) {
  unsigned u = __float_as_uint(x);
  u += 0x7fff + ((u >> 16) & 1);  // RNE
  return (unsigned short)(u >> 16);
}
__device__ inline float bf2f(unsigned short h) {
  return __uint_as_float(((unsigned)h) << 16);
}

// ---------------------------------------------------------------------------
// Merged conversions (single dispatch).
// id < 12288 : convert_x — fp32 [4096x1024] -> bf16 split [4096x2048]=[hi|lo]
// id >= 12288: convert_w — W [1024x1024] fp32 -> Wt bf16 [n][2048]=[Whi^T|Wlo^T]
// ---------------------------------------------------------------------------
__global__ __launch_bounds__(256) void convert_xw(
    const float* __restrict__ x0, const float* __restrict__ x1,
    const float* __restrict__ x2, unsigned short* __restrict__ Xs,
    const float* __restrict__ w0, const float* __restrict__ w1,
    const float* __restrict__ w2, const float* __restrict__ w3,
    unsigned short* __restrict__ Wt) {
  __shared__ float T[64][65];
  const int id = blockIdx.x;
  const int t = threadIdx.x;
  if (id < 12288) {
    int z = id >> 12;
    int bx = id & 4095;
    const float* src = z == 0 ? x0 : (z == 1 ? x1 : x2);
    unsigned short* dst = Xs + (size_t)z * XS_SLAB;
    size_t idx = ((size_t)bx * 256 + t) * 4;
    int r = (int)(idx >> 10);
    int c = (int)(idx & 1023);
    f32x4 v = *(const f32x4*)&src[idx];
    unsigned short hi[4], lo[4];
#pragma unroll
    for (int i = 0; i < 4; ++i) {
      float vi = v[i];
      hi[i] = f2bf(vi);
      lo[i] = f2bf(vi - bf2f(hi[i]));
    }
    ushort4 h4 = {hi[0], hi[1], hi[2], hi[3]};
    ushort4 l4 = {lo[0], lo[1], lo[2], lo[3]};
    *(ushort4*)&dst[(size_t)r * 2048 + c] = h4;
    *(ushort4*)&dst[(size_t)r * 2048 + 1024 + c] = l4;
  } else {
    int wid = id - 12288;
    int z = wid >> 8;
    int by = (wid >> 4) & 15;
    int bx = wid & 15;
    const float* W = z == 0 ? w0 : (z == 1 ? w1 : (z == 2 ? w2 : w3));
    unsigned short* dst = Wt + (size_t)z * WT_SLAB;
    int k0 = by * 64, n0 = bx * 64;
#pragma unroll
    for (int i = 0; i < 4; ++i) {
      int row = (t >> 4) + i * 16;
      int c4 = (t & 15) * 4;
      f32x4 v = *(const f32x4*)&W[(size_t)(k0 + row) * 1024 + n0 + c4];
      T[row][c4 + 0] = v[0]; T[row][c4 + 1] = v[1];
      T[row][c4 + 2] = v[2]; T[row][c4 + 3] = v[3];
    }
    __syncthreads();
    int n = t >> 2;
    int kc = (t & 3) * 16;
    unsigned short hi[16], lo[16];
#pragma unroll
    for (int j = 0; j < 16; ++j) {
      float x = T[kc + j][n];
      hi[j] = f2bf(x);
      lo[j] = f2bf(x - bf2f(hi[j]));
    }
    size_t base = (size_t)(n0 + n) * 2048 + k0 + kc;
#pragma unroll
    for (int j4 = 0; j4 < 4; ++j4) {
      ushort4 h4 = {hi[j4 * 4], hi[j4 * 4 + 1], hi[j4 * 4 + 2], hi[j4 * 4 + 3]};
      ushort4 l4 = {lo[j4 * 4], lo[j4 * 4 + 1], lo[j4 * 4 + 2], lo[j4 * 4 + 3]};
      *(ushort4*)&dst[base + j4 * 4] = h4;
      *(ushort4*)&dst[base + 1024 + j4 * 4] = l4;
    }
  }
}

// ---------------------------------------------------------------------------
// QKV GEMM: C[4096x1024] = A[4096x3072] @ W[3072x1024] + bias (bf16x3 split).
// 128x128 tile, global_load_lds double-buffer, XCD-swizzled block map.
// Drip-writes the full 512MB attn zero region in 12 bursts of 16KB/wave,
// each issued right after a barrier (max issue-to-drain distance).
// ---------------------------------------------------------------------------
__global__ __launch_bounds__(256, 3) void gemm_qkv(
    const unsigned short* __restrict__ Abase,
    const unsigned short* __restrict__ Wtbase,
    unsigned short* __restrict__ Cbase, const float* __restrict__ bb0,
    const float* __restrict__ bb1, const float* __restrict__ bb2,
    float* __restrict__ attnz) {
  __shared__ s16x8 As[2][512];
  __shared__ s16x8 Bs[2][512];
  int z = blockIdx.z;
  const unsigned short* A = Abase + (size_t)z * XS_SLAB;
  const unsigned short* Wt = Wtbase + (size_t)z * WT_SLAB;
  const float* bias = z == 0 ? bb0 : (z == 1 ? bb1 : bb2);
  const float scl = (z == 0) ? 0.125f : 1.0f;

  const int t = threadIdx.x;
  const int lane = t & 63, wave = t >> 6;
  const int wm = wave & 1, wn = wave >> 1;

  // XCD swizzle: flat = bn-fast id; XCD c gets bm in [4c, 4c+4) x all bn.
  const int flat = blockIdx.x + (blockIdx.y << 3);          // 0..255
  const int swz = (flat & 7) * 32 + (flat >> 3);
  const int bm = (swz >> 3) * 128, bn = (swz & 7) * 128;

  // attn-zero drip state: contiguous 192KB chunk per wave, 12 bursts of 16KB
  const int flat3 = flat + (z << 8);                        // 0..767
  const size_t zbase = (size_t)(flat3 * 4 + wave) * 196608;
  char* const az = (char*)attnz;
  const f32x4 zv = {0.f, 0.f, 0.f, 0.f};

  f32x4 acc[4][4] = {};

  const int s0 = t, s1 = t + 256;
  const int r0 = s0 >> 2, c0 = (s0 & 3) ^ ((r0 >> 1) & 3);
  const int r1 = s1 >> 2, c1 = (s1 & 3) ^ ((r1 >> 1) & 3);
  const unsigned short* A0 = A + (size_t)(bm + r0) * 2048 + c0 * 8;
  const unsigned short* A1 = A + (size_t)(bm + r1) * 2048 + c1 * 8;
  const unsigned short* B0 = Wt + (size_t)(bn + r0) * 2048 + c0 * 8;
  const unsigned short* B1 = Wt + (size_t)(bn + r1) * 2048 + c1 * 8;

  const int m15 = lane & 15, q = lane >> 4;

  gld_lds16(A0, &As[0][wave * 64]);
  gld_lds16(A1, &As[0][256 + wave * 64]);
  gld_lds16(B0, &Bs[0][wave * 64]);
  gld_lds16(B1, &Bs[0][256 + wave * 64]);
  __syncthreads();

  int cur = 0;
  for (int kb = 0; kb < 3072; kb += 32) {
    // drip burst: every 8th step, 16 NT stores issued right after the
    // barrier -> ~full body of latency-hiding before the next drain.
    if ((kb & 255) == 0) {
      size_t base = zbase + (size_t)(kb >> 8) * 16384 + (size_t)(lane << 4);
#pragma unroll
      for (int j = 0; j < 16; ++j) {
        size_t off = base + (size_t)j * 1024;
        if (off < ATTN_BYTES)
          __builtin_nontemporal_store(zv, (f32x4*)(az + off));
      }
    }

    const int kn = kb + 32;
    const bool more = (kn < 3072);
    if (more) {
      // segments: A_hi*W_hi | A_hi*W_lo | A_lo*W_hi
      int asrc = kn < 1024 ? kn : kn - 1024;
      int wsrc = kn < 2048 ? kn : kn - 2048;
      gld_lds16(A0 + asrc, &As[cur ^ 1][wave * 64]);
      gld_lds16(A1 + asrc, &As[cur ^ 1][256 + wave * 64]);
      gld_lds16(B0 + wsrc, &Bs[cur ^ 1][wave * 64]);
      gld_lds16(B1 + wsrc, &Bs[cur ^ 1][256 + wave * 64]);
    }

    s16x8 af[4], bf[4];
#pragma unroll
    for (int mt = 0; mt < 4; ++mt) {
      int r = wm * 64 + mt * 16 + m15;
      af[mt] = As[cur][r * 4 + (q ^ ((r >> 1) & 3))];
    }
#pragma unroll
    for (int nt = 0; nt < 4; ++nt) {
      int r = wn * 64 + nt * 16 + m15;
      bf[nt] = Bs[cur][r * 4 + (q ^ ((r >> 1) & 3))];
    }
#pragma unroll
    for (int mt = 0; mt < 4; ++mt)
#pragma unroll
      for (int nt = 0; nt < 4; ++nt)
        acc[mt][nt] = __builtin_amdgcn_mfma_f32_16x16x32_bf16(
            af[mt], bf[nt], acc[mt][nt], 0, 0, 0);

    if (more) {
      __syncthreads();
      cur ^= 1;
    }
  }

#pragma unroll
  for (int nt = 0; nt < 4; ++nt) {
    int col = bn + wn * 64 + nt * 16 + m15;
    float bv = bias[col];
#pragma unroll
    for (int mt = 0; mt < 4; ++mt) {
      int rowb = bm + wm * 64 + mt * 16 + q * 4;
#pragma unroll
      for (int i = 0; i < 4; ++i) {
        float val = (acc[mt][nt][i] + bv) * scl;
        (Cbase + (size_t)z * QB_SLAB)[(size_t)(rowb + i) * 1024 + col] =
            f2bf(val);
      }
    }
  }
}

// ---------------------------------------------------------------------------
// Out-projection GEMM: 64x128 tile, 512 blocks = 2/CU. XCD-swizzled.
// ---------------------------------------------------------------------------
__global__ __launch_bounds__(256, 2) void gemm_out(
    const unsigned short* __restrict__ A,   // XsAO [4096][2048]
    const unsigned short* __restrict__ Wt,  // Wo^T split [1024][2048]
    float* __restrict__ C, const float* __restrict__ bias) {
  __shared__ s16x8 As[2][256];
  __shared__ s16x8 Bs[2][512];
  const int t = threadIdx.x;
  const int lane = t & 63, wave = t >> 6;
  const int wm = wave & 1, wn = wave >> 1;

  const int flat = blockIdx.x + (blockIdx.y << 3);          // 0..511
  const int swz = (flat & 7) * 64 + (flat >> 3);
  const int bm = (swz >> 3) * 64, bn = (swz & 7) * 128;

  f32x4 acc[2][4] = {};

  const int ra = t >> 2, ca = (t & 3) ^ ((ra >> 1) & 3);
  const int s0 = t, s1 = t + 256;
  const int r0 = s0 >> 2, c0 = (s0 & 3) ^ ((r0 >> 1) & 3);
  const int r1 = s1 >> 2, c1 = (s1 & 3) ^ ((r1 >> 1) & 3);
  const unsigned short* Ap = A + (size_t)(bm + ra) * 2048 + ca * 8;
  const unsigned short* B0 = Wt + (size_t)(bn + r0) * 2048 + c0 * 8;
  const unsigned short* B1 = Wt + (size_t)(bn + r1) * 2048 + c1 * 8;

  const int m15 = lane & 15, q = lane >> 4;

  gld_lds16(Ap, &As[0][wave * 64]);
  gld_lds16(B0, &Bs[0][wave * 64]);
  gld_lds16(B1, &Bs[0][256 + wave * 64]);
  __syncthreads();

  int cur = 0;
  for (int kb = 0; kb < 3072; kb += 32) {
    const int kn = kb + 32;
    if (kn < 3072) {
      int asrc = kn < 1024 ? kn : kn - 1024;
      int wsrc = kn < 2048 ? kn : kn - 2048;
      gld_lds16(Ap + asrc, &As[cur ^ 1][wave * 64]);
      gld_lds16(B0 + wsrc, &Bs[cur ^ 1][wave * 64]);
      gld_lds16(B1 + wsrc, &Bs[cur ^ 1][256 + wave * 64]);
    }

    s16x8 af[2], bf[4];
#pragma unroll
    for (int mt = 0; mt < 2; ++mt) {
      int r = wm * 32 + mt * 16 + m15;
      af[mt] = As[cur][r * 4 + (q ^ ((r >> 1) & 3))];
    }
#pragma unroll
    for (int nt = 0; nt < 4; ++nt) {
      int r = wn * 64 + nt * 16 + m15;
      bf[nt] = Bs[cur][r * 4 + (q ^ ((r >> 1) & 3))];
    }
#pragma unroll
    for (int mt = 0; mt < 2; ++mt)
#pragma unroll
      for (int nt = 0; nt < 4; ++nt)
        acc[mt][nt] = __builtin_amdgcn_mfma_f32_16x16x32_bf16(
            af[mt], bf[nt], acc[mt][nt], 0, 0, 0);

    if (kn < 3072) {
      __syncthreads();
      cur ^= 1;
    }
  }

#pragma unroll
  for (int nt = 0; nt < 4; ++nt) {
    int col = bn + wn * 64 + nt * 16 + m15;
    float bv = bias[col];
#pragma unroll
    for (int mt = 0; mt < 2; ++mt) {
      int rowb = bm + wm * 32 + mt * 16 + q * 4;
#pragma unroll
      for (int i = 0; i < 4; ++i) {
        __builtin_nontemporal_store(
            acc[mt][nt][i] + bv, &C[(size_t)(rowb + i) * 1024 + col]);
      }
    }
  }
}

// ---------------------------------------------------------------------------
// Vb [4096][1024] bf16 -> Vt [b][h][d][s] bf16 (per-head transposed).
// ---------------------------------------------------------------------------
__global__ __launch_bounds__(256) void transpose_v(
    const unsigned short* __restrict__ Vb, unsigned short* __restrict__ Vt) {
  __shared__ unsigned short T[64][88];
  const int b = blockIdx.z, h = blockIdx.y, s0 = blockIdx.x * 64;
  const int t = threadIdx.x;
  {
    int row = t >> 2, part = t & 3;
    const unsigned short* src =
        Vb + (size_t)(b * Ss + s0 + row) * 1024 + h * 64 + part * 16;
    s16x8 v0 = *(const s16x8*)src;
    s16x8 v1 = *(const s16x8*)(src + 8);
    *(s16x8*)&T[row][part * 16] = v0;
    *(s16x8*)&T[row][part * 16 + 8] = v1;
  }
  __syncthreads();
  {
    int d = t & 63, sw = t >> 6;
    unsigned short tmp[16];
#pragma unroll
    for (int i = 0; i < 16; ++i) tmp[i] = T[sw * 16 + i][d];
    unsigned short* dst =
        Vt + ((size_t)((b * Hh + h) * 64 + d)) * 2048 + s0 + sw * 16;
    *(s16x8*)dst = *(const s16x8*)&tmp[0];
    *(s16x8*)(dst + 8) = *(const s16x8*)&tmp[8];
  }
}

// ---------------------------------------------------------------------------
// Fused attention v6: per block = one (b,h) x 16-query tile, 4 waves.
// XCD-contiguous swizzle: XCD x owns logical tiles [x*512,(x+1)*512) = 4 full
// (b,h) panels -> concurrent K/V L2 footprint ~512KB/XCD (no thrash).
// S1: scores (fp32) via MFMA -> LDS P.  S2: softmax; band-only global write
// from regs; probs stored bf16 OVERLAID on P row (row fully consumed first).
// S3: PV reads bf16 probs directly (no f2bf chain).
// ---------------------------------------------------------------------------
constexpr int SW3 = 556;  // f32 stride: 556%32=12 -> <=2-way banks; 16B-aligned
__global__ __launch_bounds__(256) void attn_v6(
    const unsigned short* __restrict__ Qb, const unsigned short* __restrict__ Kb,
    const unsigned short* __restrict__ Vt, float* __restrict__ attn,
    unsigned short* __restrict__ XsAO) {
  __shared__ float P[16 * SW3];  // 35.6 KB
  const int t = threadIdx.x;
  const int lane = t & 63, wave = t >> 6;
  const int m15 = lane & 15, quad = lane >> 4;
  const int bid0 = blockIdx.x;
  const int bid = (bid0 & 7) * 512 + (bid0 >> 3);  // XCD-contiguous (4096=8*512)
  const int qt = bid & 127, h = (bid >> 7) & 15, b = bid >> 11;
  const int q0 = qt * 16;
  int jlo = q0 - WINw; if (jlo < 0) jlo = 0;
  int jhi = q0 + 15 + WINw; if (jhi > Ss - 1) jhi = Ss - 1;
  const int ncols = jhi - jlo + 1;  // multiple of 16, <=528
  const int ntiles = ncols >> 4;

  // ---- stage 1: scores via MFMA -> P (fp32) ----
  {
    const unsigned short* qrow =
        Qb + (size_t)(b * Ss + q0 + m15) * 1024 + h * 64 + quad * 8;
    s16x8 aq0 = *(const s16x8*)qrow;
    s16x8 aq1 = *(const s16x8*)(qrow + 32);
    for (int nt = wave; nt < ntiles; nt += 4) {
      const unsigned short* krow =
          Kb + (size_t)(b * Ss + jlo + nt * 16 + m15) * 1024 + h * 64 + quad * 8;
      s16x8 b0 = *(const s16x8*)krow;
      s16x8 b1 = *(const s16x8*)(krow + 32);
      f32x4 c = {0.f, 0.f, 0.f, 0.f};
      __builtin_amdgcn_s_setprio(1);
      c = __builtin_amdgcn_mfma_f32_16x16x32_bf16(aq0, b0, c, 0, 0, 0);
      c = __builtin_amdgcn_mfma_f32_16x16x32_bf16(aq1, b1, c, 0, 0, 0);
      __builtin_amdgcn_s_setprio(0);
      float* pp = &P[(quad * 4) * SW3 + nt * 16 + m15];
#pragma unroll
      for (int i = 0; i < 4; ++i) pp[i * SW3] = c[i];
    }
  }
  lgkm_barrier();

  // ---- stage 2: softmax; band global write; bf16 probs overlay into P ----
  {
#pragma unroll
    for (int ri = 0; ri < 4; ++ri) {
      const int r = wave * 4 + ri;
      const int qq = q0 + r;
      int lo = qq - WINw; if (lo < 0) lo = 0;
      int hi = qq + WINw; if (hi > Ss - 1) hi = Ss - 1;
      const int clo = lo - jlo, chi = hi - jlo;
      float sv[9];
      bool ib[9];
      float m = -1e30f;
#pragma unroll
      for (int k2 = 0; k2 < 9; ++k2) {
        int c = k2 * 64 + lane;
        bool inb = (c >= clo) && (c <= chi);
        ib[k2] = inb;
        float vv = inb ? P[r * SW3 + c] : -1e30f;
        sv[k2] = vv;
        m = fmaxf(m, vv);
      }
#pragma unroll
      for (int off = 32; off; off >>= 1) m = fmaxf(m, __shfl_xor(m, off, 64));
      float e[9], l = 0.f;
#pragma unroll
      for (int k2 = 0; k2 < 9; ++k2) { e[k2] = __expf(sv[k2] - m); l += e[k2]; }
#pragma unroll
      for (int off = 32; off; off >>= 1) l += __shfl_xor(l, off, 64);
      const float inv = 1.f / l;
      // overlay: row r's fp32 scores fully consumed into sv[] above
      unsigned short* pb = (unsigned short*)&P[r * SW3];
      float* arow = attn + ((size_t)((b * Hh + h) * Ss + qq)) * Ss + jlo;
#pragma unroll
      for (int k2 = 0; k2 < 9; ++k2) {
        int c = k2 * 64 + lane;
        float w = ib[k2] ? e[k2] * inv : 0.f;
        if (c < 544) pb[c] = f2bf(w);
        if (c < ncols) __builtin_nontemporal_store(w, &arow[c]);
      }
    }
  }
  lgkm_barrier();

  // ---- stage 3: PV via MFMA; wave = d-tile; A-frags read bf16 from P ----
  {
    const int ntk = (ncols + 31) >> 5;
    const unsigned short* vtrow =
        Vt + ((size_t)((b * Hh + h) * 64 + wave * 16 + m15)) * 2048 + jlo +
        quad * 8;
    f32x4 o = {0.f, 0.f, 0.f, 0.f};
    const unsigned short* pbrow = (const unsigned short*)&P[m15 * SW3];
    for (int ks = 0; ks < ntk; ++ks) {
      s16x8 af = *(const s16x8*)&pbrow[ks * 32 + quad * 8];
      s16x8 bf = *(const s16x8*)(vtrow + ks * 32);
      __builtin_amdgcn_s_setprio(1);
      o = __builtin_amdgcn_mfma_f32_16x16x32_bf16(af, bf, o, 0, 0, 0);
      __builtin_amdgcn_s_setprio(0);
    }
    const int dcol = h * 64 + wave * 16 + m15;
#pragma unroll
    for (int i = 0; i < 4; ++i) {
      int row = q0 + quad * 4 + i;
      unsigned short hi = f2bf(o[i]);
      unsigned short lo = f2bf(o[i] - bf2f(hi));
      unsigned short* dst = XsAO + (size_t)(b * Ss + row) * 2048 + dcol;
      dst[0] = hi;
      dst[1024] = lo;
    }
  }
}

// ---------------------------------------------------------------------------
extern "C" void kernel_launch(void* const* d_in, const int* in_sizes, int n_in,
                              void* d_out, int out_size, void* d_ws,
                              size_t ws_size, hipStream_t stream) {
  const float* q  = (const float*)d_in[0];
  const float* k  = (const float*)d_in[1];
  const float* v  = (const float*)d_in[2];
  const float* Wq = (const float*)d_in[3];
  const float* bq = (const float*)d_in[4];
  const float* Wk = (const float*)d_in[5];
  const float* bk = (const float*)d_in[6];
  const float* Wv = (const float*)d_in[7];
  const float* bv = (const float*)d_in[8];
  const float* Wo = (const float*)d_in[9];
  const float* bo = (const float*)d_in[10];

  float* out = (float*)d_out;
  float* attn = out + (size_t)Bb * Ss * Dd;

  unsigned short* Xs   = (unsigned short*)d_ws;   // 48 MB
  unsigned short* XsAO = Xs + 3 * XS_SLAB;        // 16 MB
  unsigned short* Wt   = XsAO + XS_SLAB;          // 16 MB
  unsigned short* Qb   = Wt + 4 * WT_SLAB;        // 8 MB
  unsigned short* Kb   = Qb + QB_SLAB;            // 8 MB
  unsigned short* Vb   = Kb + QB_SLAB;            // 8 MB
  unsigned short* Vt   = Vb + QB_SLAB;            // 8 MB (+slack after)

  hipLaunchKernelGGL(convert_xw, dim3(12288 + 1024), dim3(256), 0, stream,
                     q, k, v, Xs, Wq, Wk, Wv, Wo, Wt);
  hipLaunchKernelGGL(gemm_qkv, dim3(8, 32, 3), dim3(256), 0, stream,
                     Xs, Wt, Qb, bq, bk, bv, attn);
  hipLaunchKernelGGL(transpose_v, dim3(32, 16, 2), dim3(256), 0, stream,
                     Vb, Vt);
  hipLaunchKernelGGL(attn_v6, dim3(Bb * Hh * (Ss / 16)), dim3(256), 0, stream,
                     Qb, Kb, Vt, attn, XsAO);
  hipLaunchKernelGGL(gemm_out, dim3(8, 64, 1), dim3(256), 0, stream,
                     XsAO, Wt + 3 * WT_SLAB, out, bo);
}

// Round 7
// 759.658 us; speedup vs baseline: 1.2444x; 1.0297x over previous
//
#include <hip/hip_runtime.h>

// B=2, S=2048, D=1024, H=16, d_k=64, WINDOW=256
// d_out = out [B,S,D] fp32  ++  attn [B,H,S,S] fp32
// ws (112 MB): Xs bf16 3x[4096x2048] | XsAO bf16 [4096x2048] | Wt bf16 4x[1024x2048]
//              | Qb,Kb,Vb bf16 [4096x1024] | Vt bf16 [B,H,64,2048]
//
// v9: Q/K projections use bf16x2 (K=2048: A_hi*W_hi + A_hi*W_lo, dropping
// A_lo*W_hi — scores only need ~1e-2 accuracy, softmax is contractive).
// V keeps bf16x3 (out-precision path). No zero drip: attn writes its full
// rows (band values + vectorized zero fill) — 6 rounds showed moving the
// 512MB write between kernels is perf-neutral; simplest form wins.

constexpr int Bb = 2, Ss = 2048, Dd = 1024, Hh = 16, WINw = 256;
constexpr size_t XS_SLAB = (size_t)4096 * 2048;  // bf16 elems
constexpr size_t WT_SLAB = (size_t)1024 * 2048;  // bf16 elems
constexpr size_t QB_SLAB = (size_t)4096 * 1024;  // bf16 elems

typedef short s16x8 __attribute__((ext_vector_type(8)));
typedef float f32x4 __attribute__((ext_vector_type(4)));

typedef __attribute__((address_space(3))) unsigned int lds_uint;
typedef const __attribute__((address_space(1))) unsigned int gbl_uint;

// async global->LDS, 16B per lane; LDS dest = wave-uniform base + lane*16
__device__ __forceinline__ void gld_lds16(const void* g, void* l) {
  __builtin_amdgcn_global_load_lds((gbl_uint*)g, (lds_uint*)l, 16, 0, 0);
}

// LDS-only drain + barrier (lets global stores keep draining across it)
__device__ __forceinline__ void lgkm_barrier() {
  asm volatile("s_waitcnt lgkmcnt(0)" ::: "memory");
  __builtin_amdgcn_s_barrier();
}

__device__ inline unsigned short f2bf(float x) {
  unsigned u = __float_as_uint(x);
  u += 0x7fff + ((u >> 16) & 1);  // RNE
  return (unsigned short)(u >> 16);
}
__device__ inline float bf2f(unsigned short h) {
  return __uint_as_float(((unsigned)h) << 16);
}

// ---------------------------------------------------------------------------
// Merged conversions (single dispatch).
// id < 12288 : convert_x — fp32 [4096x1024] -> bf16 split [4096x2048]=[hi|lo]
//              (lo half skipped for z<2: only V's lo is ever read)
// id >= 12288: convert_w — W [1024x1024] fp32 -> Wt bf16 [n][2048]=[Whi^T|Wlo^T]
// ---------------------------------------------------------------------------
__global__ __launch_bounds__(256) void convert_xw(
    const float* __restrict__ x0, const float* __restrict__ x1,
    const float* __restrict__ x2, unsigned short* __restrict__ Xs,
    const float* __restrict__ w0, const float* __restrict__ w1,
    const float* __restrict__ w2, const float* __restrict__ w3,
    unsigned short* __restrict__ Wt) {
  __shared__ float T[64][65];
  const int id = blockIdx.x;
  const int t = threadIdx.x;
  if (id < 12288) {
    int z = id >> 12;
    int bx = id & 4095;
    const float* src = z == 0 ? x0 : (z == 1 ? x1 : x2);
    unsigned short* dst = Xs + (size_t)z * XS_SLAB;
    size_t idx = ((size_t)bx * 256 + t) * 4;
    int r = (int)(idx >> 10);
    int c = (int)(idx & 1023);
    f32x4 v = *(const f32x4*)&src[idx];
    unsigned short hi[4], lo[4];
#pragma unroll
    for (int i = 0; i < 4; ++i) {
      float vi = v[i];
      hi[i] = f2bf(vi);
      lo[i] = f2bf(vi - bf2f(hi[i]));
    }
    ushort4 h4 = {hi[0], hi[1], hi[2], hi[3]};
    ushort4 l4 = {lo[0], lo[1], lo[2], lo[3]};
    *(ushort4*)&dst[(size_t)r * 2048 + c] = h4;
    if (z == 2)  // lo half only consumed by the V projection (bf16x3)
      *(ushort4*)&dst[(size_t)r * 2048 + 1024 + c] = l4;
  } else {
    int wid = id - 12288;
    int z = wid >> 8;
    int by = (wid >> 4) & 15;
    int bx = wid & 15;
    const float* W = z == 0 ? w0 : (z == 1 ? w1 : (z == 2 ? w2 : w3));
    unsigned short* dst = Wt + (size_t)z * WT_SLAB;
    int k0 = by * 64, n0 = bx * 64;
#pragma unroll
    for (int i = 0; i < 4; ++i) {
      int row = (t >> 4) + i * 16;
      int c4 = (t & 15) * 4;
      f32x4 v = *(const f32x4*)&W[(size_t)(k0 + row) * 1024 + n0 + c4];
      T[row][c4 + 0] = v[0]; T[row][c4 + 1] = v[1];
      T[row][c4 + 2] = v[2]; T[row][c4 + 3] = v[3];
    }
    __syncthreads();
    int n = t >> 2;
    int kc = (t & 3) * 16;
    unsigned short hi[16], lo[16];
#pragma unroll
    for (int j = 0; j < 16; ++j) {
      float x = T[kc + j][n];
      hi[j] = f2bf(x);
      lo[j] = f2bf(x - bf2f(hi[j]));
    }
    size_t base = (size_t)(n0 + n) * 2048 + k0 + kc;
#pragma unroll
    for (int j4 = 0; j4 < 4; ++j4) {
      ushort4 h4 = {hi[j4 * 4], hi[j4 * 4 + 1], hi[j4 * 4 + 2], hi[j4 * 4 + 3]};
      ushort4 l4 = {lo[j4 * 4], lo[j4 * 4 + 1], lo[j4 * 4 + 2], lo[j4 * 4 + 3]};
      *(ushort4*)&dst[base + j4 * 4] = h4;
      *(ushort4*)&dst[base + 1024 + j4 * 4] = l4;
    }
  }
}

// ---------------------------------------------------------------------------
// QKV GEMM: C[4096x1024] = A[4096xK] @ W[Kx1024] + bias.
// z=0 (Q), z=1 (K): bf16x2, K=2048 (A_hi*W_hi + A_hi*W_lo).
// z=2 (V):          bf16x3, K=3072 (+ A_lo*W_hi).
// 128x128 tile, global_load_lds double-buffer, XCD-swizzled block map.
// ---------------------------------------------------------------------------
__global__ __launch_bounds__(256, 3) void gemm_qkv(
    const unsigned short* __restrict__ Abase,
    const unsigned short* __restrict__ Wtbase,
    unsigned short* __restrict__ Cbase, const float* __restrict__ bb0,
    const float* __restrict__ bb1, const float* __restrict__ bb2) {
  __shared__ s16x8 As[2][512];
  __shared__ s16x8 Bs[2][512];
  int z = blockIdx.z;
  const unsigned short* A = Abase + (size_t)z * XS_SLAB;
  const unsigned short* Wt = Wtbase + (size_t)z * WT_SLAB;
  const float* bias = z == 0 ? bb0 : (z == 1 ? bb1 : bb2);
  const float scl = (z == 0) ? 0.125f : 1.0f;
  const int KMAX = (z == 2) ? 3072 : 2048;

  const int t = threadIdx.x;
  const int lane = t & 63, wave = t >> 6;
  const int wm = wave & 1, wn = wave >> 1;

  // XCD swizzle: flat = bn-fast id; XCD c gets bm in [4c, 4c+4) x all bn.
  const int flat = blockIdx.x + (blockIdx.y << 3);          // 0..255
  const int swz = (flat & 7) * 32 + (flat >> 3);
  const int bm = (swz >> 3) * 128, bn = (swz & 7) * 128;

  f32x4 acc[4][4] = {};

  const int s0 = t, s1 = t + 256;
  const int r0 = s0 >> 2, c0 = (s0 & 3) ^ ((r0 >> 1) & 3);
  const int r1 = s1 >> 2, c1 = (s1 & 3) ^ ((r1 >> 1) & 3);
  const unsigned short* A0 = A + (size_t)(bm + r0) * 2048 + c0 * 8;
  const unsigned short* A1 = A + (size_t)(bm + r1) * 2048 + c1 * 8;
  const unsigned short* B0 = Wt + (size_t)(bn + r0) * 2048 + c0 * 8;
  const unsigned short* B1 = Wt + (size_t)(bn + r1) * 2048 + c1 * 8;

  const int m15 = lane & 15, q = lane >> 4;

  gld_lds16(A0, &As[0][wave * 64]);
  gld_lds16(A1, &As[0][256 + wave * 64]);
  gld_lds16(B0, &Bs[0][wave * 64]);
  gld_lds16(B1, &Bs[0][256 + wave * 64]);
  __syncthreads();

  int cur = 0;
  for (int kb = 0; kb < KMAX; kb += 32) {
    const int kn = kb + 32;
    const bool more = (kn < KMAX);
    if (more) {
      // virtual-K segments: A_hi*W_hi | A_hi*W_lo | (z=2 only) A_lo*W_hi
      int asrc = kn < 1024 ? kn : kn - 1024;
      int wsrc = kn < 2048 ? kn : kn - 2048;
      gld_lds16(A0 + asrc, &As[cur ^ 1][wave * 64]);
      gld_lds16(A1 + asrc, &As[cur ^ 1][256 + wave * 64]);
      gld_lds16(B0 + wsrc, &Bs[cur ^ 1][wave * 64]);
      gld_lds16(B1 + wsrc, &Bs[cur ^ 1][256 + wave * 64]);
    }

    s16x8 af[4], bf[4];
#pragma unroll
    for (int mt = 0; mt < 4; ++mt) {
      int r = wm * 64 + mt * 16 + m15;
      af[mt] = As[cur][r * 4 + (q ^ ((r >> 1) & 3))];
    }
#pragma unroll
    for (int nt = 0; nt < 4; ++nt) {
      int r = wn * 64 + nt * 16 + m15;
      bf[nt] = Bs[cur][r * 4 + (q ^ ((r >> 1) & 3))];
    }
#pragma unroll
    for (int mt = 0; mt < 4; ++mt)
#pragma unroll
      for (int nt = 0; nt < 4; ++nt)
        acc[mt][nt] = __builtin_amdgcn_mfma_f32_16x16x32_bf16(
            af[mt], bf[nt], acc[mt][nt], 0, 0, 0);

    if (more) {
      __syncthreads();
      cur ^= 1;
    }
  }

#pragma unroll
  for (int nt = 0; nt < 4; ++nt) {
    int col = bn + wn * 64 + nt * 16 + m15;
    float bv = bias[col];
#pragma unroll
    for (int mt = 0; mt < 4; ++mt) {
      int rowb = bm + wm * 64 + mt * 16 + q * 4;
#pragma unroll
      for (int i = 0; i < 4; ++i) {
        float val = (acc[mt][nt][i] + bv) * scl;
        (Cbase + (size_t)z * QB_SLAB)[(size_t)(rowb + i) * 1024 + col] =
            f2bf(val);
      }
    }
  }
}

// ---------------------------------------------------------------------------
// Out-projection GEMM: 64x128 tile, 512 blocks = 2/CU. XCD-swizzled. bf16x3.
// ---------------------------------------------------------------------------
__global__ __launch_bounds__(256, 2) void gemm_out(
    const unsigned short* __restrict__ A,   // XsAO [4096][2048]
    const unsigned short* __restrict__ Wt,  // Wo^T split [1024][2048]
    float* __restrict__ C, const float* __restrict__ bias) {
  __shared__ s16x8 As[2][256];
  __shared__ s16x8 Bs[2][512];
  const int t = threadIdx.x;
  const int lane = t & 63, wave = t >> 6;
  const int wm = wave & 1, wn = wave >> 1;

  const int flat = blockIdx.x + (blockIdx.y << 3);          // 0..511
  const int swz = (flat & 7) * 64 + (flat >> 3);
  const int bm = (swz >> 3) * 64, bn = (swz & 7) * 128;

  f32x4 acc[2][4] = {};

  const int ra = t >> 2, ca = (t & 3) ^ ((ra >> 1) & 3);
  const int s0 = t, s1 = t + 256;
  const int r0 = s0 >> 2, c0 = (s0 & 3) ^ ((r0 >> 1) & 3);
  const int r1 = s1 >> 2, c1 = (s1 & 3) ^ ((r1 >> 1) & 3);
  const unsigned short* Ap = A + (size_t)(bm + ra) * 2048 + ca * 8;
  const unsigned short* B0 = Wt + (size_t)(bn + r0) * 2048 + c0 * 8;
  const unsigned short* B1 = Wt + (size_t)(bn + r1) * 2048 + c1 * 8;

  const int m15 = lane & 15, q = lane >> 4;

  gld_lds16(Ap, &As[0][wave * 64]);
  gld_lds16(B0, &Bs[0][wave * 64]);
  gld_lds16(B1, &Bs[0][256 + wave * 64]);
  __syncthreads();

  int cur = 0;
  for (int kb = 0; kb < 3072; kb += 32) {
    const int kn = kb + 32;
    if (kn < 3072) {
      int asrc = kn < 1024 ? kn : kn - 1024;
      int wsrc = kn < 2048 ? kn : kn - 2048;
      gld_lds16(Ap + asrc, &As[cur ^ 1][wave * 64]);
      gld_lds16(B0 + wsrc, &Bs[cur ^ 1][wave * 64]);
      gld_lds16(B1 + wsrc, &Bs[cur ^ 1][256 + wave * 64]);
    }

    s16x8 af[2], bf[4];
#pragma unroll
    for (int mt = 0; mt < 2; ++mt) {
      int r = wm * 32 + mt * 16 + m15;
      af[mt] = As[cur][r * 4 + (q ^ ((r >> 1) & 3))];
    }
#pragma unroll
    for (int nt = 0; nt < 4; ++nt) {
      int r = wn * 64 + nt * 16 + m15;
      bf[nt] = Bs[cur][r * 4 + (q ^ ((r >> 1) & 3))];
    }
#pragma unroll
    for (int mt = 0; mt < 2; ++mt)
#pragma unroll
      for (int nt = 0; nt < 4; ++nt)
        acc[mt][nt] = __builtin_amdgcn_mfma_f32_16x16x32_bf16(
            af[mt], bf[nt], acc[mt][nt], 0, 0, 0);

    if (kn < 3072) {
      __syncthreads();
      cur ^= 1;
    }
  }

#pragma unroll
  for (int nt = 0; nt < 4; ++nt) {
    int col = bn + wn * 64 + nt * 16 + m15;
    float bv = bias[col];
#pragma unroll
    for (int mt = 0; mt < 2; ++mt) {
      int rowb = bm + wm * 32 + mt * 16 + q * 4;
#pragma unroll
      for (int i = 0; i < 4; ++i) {
        __builtin_nontemporal_store(
            acc[mt][nt][i] + bv, &C[(size_t)(rowb + i) * 1024 + col]);
      }
    }
  }
}

// ---------------------------------------------------------------------------
// Vb [4096][1024] bf16 -> Vt [b][h][d][s] bf16 (per-head transposed).
// ---------------------------------------------------------------------------
__global__ __launch_bounds__(256) void transpose_v(
    const unsigned short* __restrict__ Vb, unsigned short* __restrict__ Vt) {
  __shared__ unsigned short T[64][88];
  const int b = blockIdx.z, h = blockIdx.y, s0 = blockIdx.x * 64;
  const int t = threadIdx.x;
  {
    int row = t >> 2, part = t & 3;
    const unsigned short* src =
        Vb + (size_t)(b * Ss + s0 + row) * 1024 + h * 64 + part * 16;
    s16x8 v0 = *(const s16x8*)src;
    s16x8 v1 = *(const s16x8*)(src + 8);
    *(s16x8*)&T[row][part * 16] = v0;
    *(s16x8*)&T[row][part * 16 + 8] = v1;
  }
  __syncthreads();
  {
    int d = t & 63, sw = t >> 6;
    unsigned short tmp[16];
#pragma unroll
    for (int i = 0; i < 16; ++i) tmp[i] = T[sw * 16 + i][d];
    unsigned short* dst =
        Vt + ((size_t)((b * Hh + h) * 64 + d)) * 2048 + s0 + sw * 16;
    *(s16x8*)dst = *(const s16x8*)&tmp[0];
    *(s16x8*)(dst + 8) = *(const s16x8*)&tmp[8];
  }
}

// ---------------------------------------------------------------------------
// Fused attention v7: per block = one (b,h) x 16-query tile, 4 waves.
// XCD-contiguous swizzle. S1: scores via MFMA -> LDS P (fp32).
// S2: softmax; full-row attn write (band scalar from regs + f32x4 zero fill
// outside the band); bf16 probs overlaid on P row. S3: PV reads bf16 probs.
// ---------------------------------------------------------------------------
constexpr int SW3 = 556;  // f32 stride: 556%32=12 -> <=2-way banks; 16B-aligned
__global__ __launch_bounds__(256) void attn_v7(
    const unsigned short* __restrict__ Qb, const unsigned short* __restrict__ Kb,
    const unsigned short* __restrict__ Vt, float* __restrict__ attn,
    unsigned short* __restrict__ XsAO) {
  __shared__ float P[16 * SW3];  // 35.6 KB
  const int t = threadIdx.x;
  const int lane = t & 63, wave = t >> 6;
  const int m15 = lane & 15, quad = lane >> 4;
  const int bid0 = blockIdx.x;
  const int bid = (bid0 & 7) * 512 + (bid0 >> 3);  // XCD-contiguous (4096=8*512)
  const int qt = bid & 127, h = (bid >> 7) & 15, b = bid >> 11;
  const int q0 = qt * 16;
  int jlo = q0 - WINw; if (jlo < 0) jlo = 0;
  int jhi = q0 + 15 + WINw; if (jhi > Ss - 1) jhi = Ss - 1;
  const int ncols = jhi - jlo + 1;  // multiple of 16, <=528
  const int ntiles = ncols >> 4;

  // ---- stage 1: scores via MFMA -> P (fp32) ----
  {
    const unsigned short* qrow =
        Qb + (size_t)(b * Ss + q0 + m15) * 1024 + h * 64 + quad * 8;
    s16x8 aq0 = *(const s16x8*)qrow;
    s16x8 aq1 = *(const s16x8*)(qrow + 32);
    for (int nt = wave; nt < ntiles; nt += 4) {
      const unsigned short* krow =
          Kb + (size_t)(b * Ss + jlo + nt * 16 + m15) * 1024 + h * 64 + quad * 8;
      s16x8 b0 = *(const s16x8*)krow;
      s16x8 b1 = *(const s16x8*)(krow + 32);
      f32x4 c = {0.f, 0.f, 0.f, 0.f};
      __builtin_amdgcn_s_setprio(1);
      c = __builtin_amdgcn_mfma_f32_16x16x32_bf16(aq0, b0, c, 0, 0, 0);
      c = __builtin_amdgcn_mfma_f32_16x16x32_bf16(aq1, b1, c, 0, 0, 0);
      __builtin_amdgcn_s_setprio(0);
      float* pp = &P[(quad * 4) * SW3 + nt * 16 + m15];
#pragma unroll
      for (int i = 0; i < 4; ++i) pp[i * SW3] = c[i];
    }
  }
  lgkm_barrier();

  // ---- stage 2: softmax; full-row attn write; bf16 probs overlay into P ----
  {
    const f32x4 zv = {0.f, 0.f, 0.f, 0.f};
#pragma unroll
    for (int ri = 0; ri < 4; ++ri) {
      const int r = wave * 4 + ri;
      const int qq = q0 + r;
      int lo = qq - WINw; if (lo < 0) lo = 0;
      int hi = qq + WINw; if (hi > Ss - 1) hi = Ss - 1;
      const int clo = lo - jlo, chi = hi - jlo;
      float sv[9];
      bool ib[9];
      float m = -1e30f;
#pragma unroll
      for (int k2 = 0; k2 < 9; ++k2) {
        int c = k2 * 64 + lane;
        bool inb = (c >= clo) && (c <= chi);
        ib[k2] = inb;
        float vv = inb ? P[r * SW3 + c] : -1e30f;
        sv[k2] = vv;
        m = fmaxf(m, vv);
      }
#pragma unroll
      for (int off = 32; off; off >>= 1) m = fmaxf(m, __shfl_xor(m, off, 64));
      float e[9], l = 0.f;
#pragma unroll
      for (int k2 = 0; k2 < 9; ++k2) { e[k2] = __expf(sv[k2] - m); l += e[k2]; }
#pragma unroll
      for (int off = 32; off; off >>= 1) l += __shfl_xor(l, off, 64);
      const float inv = 1.f / l;
      // overlay: row r's fp32 scores fully consumed into sv[] above
      unsigned short* pb = (unsigned short*)&P[r * SW3];
      float* arow0 = attn + ((size_t)((b * Hh + h) * Ss + qq)) * Ss;
      float* arow = arow0 + jlo;
#pragma unroll
      for (int k2 = 0; k2 < 9; ++k2) {
        int c = k2 * 64 + lane;
        float w = ib[k2] ? e[k2] * inv : 0.f;
        if (c < 544) pb[c] = f2bf(w);
        if (c < ncols) __builtin_nontemporal_store(w, &arow[c]);
      }
      // zero fill outside the band (cols [0,jlo) and [jlo+ncols, 2048))
#pragma unroll
      for (int i = 0; i < 8; ++i) {
        int col = i * 256 + lane * 4;
        if (col < jlo || col >= jlo + ncols)
          __builtin_nontemporal_store(zv, (f32x4*)&arow0[col]);
      }
    }
  }
  lgkm_barrier();

  // ---- stage 3: PV via MFMA; wave = d-tile; A-frags read bf16 from P ----
  {
    const int ntk = (ncols + 31) >> 5;
    const unsigned short* vtrow =
        Vt + ((size_t)((b * Hh + h) * 64 + wave * 16 + m15)) * 2048 + jlo +
        quad * 8;
    f32x4 o = {0.f, 0.f, 0.f, 0.f};
    const unsigned short* pbrow = (const unsigned short*)&P[m15 * SW3];
    for (int ks = 0; ks < ntk; ++ks) {
      s16x8 af = *(const s16x8*)&pbrow[ks * 32 + quad * 8];
      s16x8 bf = *(const s16x8*)(vtrow + ks * 32);
      __builtin_amdgcn_s_setprio(1);
      o = __builtin_amdgcn_mfma_f32_16x16x32_bf16(af, bf, o, 0, 0, 0);
      __builtin_amdgcn_s_setprio(0);
    }
    const int dcol = h * 64 + wave * 16 + m15;
#pragma unroll
    for (int i = 0; i < 4; ++i) {
      int row = q0 + quad * 4 + i;
      unsigned short hi = f2bf(o[i]);
      unsigned short lo = f2bf(o[i] - bf2f(hi));
      unsigned short* dst = XsAO + (size_t)(b * Ss + row) * 2048 + dcol;
      dst[0] = hi;
      dst[1024] = lo;
    }
  }
}

// ---------------------------------------------------------------------------
extern "C" void kernel_launch(void* const* d_in, const int* in_sizes, int n_in,
                              void* d_out, int out_size, void* d_ws,
                              size_t ws_size, hipStream_t stream) {
  const float* q  = (const float*)d_in[0];
  const float* k  = (const float*)d_in[1];
  const float* v  = (const float*)d_in[2];
  const float* Wq = (const float*)d_in[3];
  const float* bq = (const float*)d_in[4];
  const float* Wk = (const float*)d_in[5];
  const float* bk = (const float*)d_in[6];
  const float* Wv = (const float*)d_in[7];
  const float* bv = (const float*)d_in[8];
  const float* Wo = (const float*)d_in[9];
  const float* bo = (const float*)d_in[10];

  float* out = (float*)d_out;
  float* attn = out + (size_t)Bb * Ss * Dd;

  unsigned short* Xs   = (unsigned short*)d_ws;   // 48 MB
  unsigned short* XsAO = Xs + 3 * XS_SLAB;        // 16 MB
  unsigned short* Wt   = XsAO + XS_SLAB;          // 16 MB
  unsigned short* Qb   = Wt + 4 * WT_SLAB;        // 8 MB
  unsigned short* Kb   = Qb + QB_SLAB;            // 8 MB
  unsigned short* Vb   = Kb + QB_SLAB;            // 8 MB
  unsigned short* Vt   = Vb + QB_SLAB;            // 8 MB (+slack after)

  hipLaunchKernelGGL(convert_xw, dim3(12288 + 1024), dim3(256), 0, stream,
                     q, k, v, Xs, Wq, Wk, Wv, Wo, Wt);
  hipLaunchKernelGGL(gemm_qkv, dim3(8, 32, 3), dim3(256), 0, stream,
                     Xs, Wt, Qb, bq, bk, bv);
  hipLaunchKernelGGL(transpose_v, dim3(32, 16, 2), dim3(256), 0, stream,
                     Vb, Vt);
  hipLaunchKernelGGL(attn_v7, dim3(Bb * Hh * (Ss / 16)), dim3(256), 0, stream,
                     Qb, Kb, Vt, attn, XsAO);
  hipLaunchKernelGGL(gemm_out, dim3(8, 64, 1), dim3(256), 0, stream,
                     XsAO, Wt + 3 * WT_SLAB, out, bo);
}

// Round 8
// 757.743 us; speedup vs baseline: 1.2475x; 1.0025x over previous
//
#include <hip/hip_runtime.h>

// B=2, S=2048, D=1024, H=16, d_k=64, WINDOW=256
// d_out = out [B,S,D] fp32  ++  attn [B,H,S,S] fp32
// ws (112 MB): Xs 3x[4096x2048] | XsAO [4096x2048] | Wt 4x[1024x2048]
//              | Qb,Kb,Vb bf16 [4096x1024] | Vt bf16 [B,H,64,2048]
//
// v10: Q/K projections are a SINGLE f16 GEMM (K=1024) — error (~1e-3 on q)
// is dominated by the bf16 Qb/Kb storage (~4e-3) that already exists, so
// absmax is unchanged. V stays bf16x3 (K=3072) for the out-precision path.
// Slab layouts unchanged (z<2 slabs use cols [0,1024) as f16).

constexpr int Bb = 2, Ss = 2048, Dd = 1024, Hh = 16, WINw = 256;
constexpr size_t XS_SLAB = (size_t)4096 * 2048;  // elems
constexpr size_t WT_SLAB = (size_t)1024 * 2048;  // elems
constexpr size_t QB_SLAB = (size_t)4096 * 1024;  // elems

typedef short s16x8 __attribute__((ext_vector_type(8)));
typedef _Float16 h16x8 __attribute__((ext_vector_type(8)));
typedef float f32x4 __attribute__((ext_vector_type(4)));

typedef __attribute__((address_space(3))) unsigned int lds_uint;
typedef const __attribute__((address_space(1))) unsigned int gbl_uint;

// async global->LDS, 16B per lane; LDS dest = wave-uniform base + lane*16
__device__ __forceinline__ void gld_lds16(const void* g, void* l) {
  __builtin_amdgcn_global_load_lds((gbl_uint*)g, (lds_uint*)l, 16, 0, 0);
}

// LDS-only drain + barrier (lets global stores keep draining across it)
__device__ __forceinline__ void lgkm_barrier() {
  asm volatile("s_waitcnt lgkmcnt(0)" ::: "memory");
  __builtin_amdgcn_s_barrier();
}

__device__ inline unsigned short f2bf(float x) {
  unsigned u = __float_as_uint(x);
  u += 0x7fff + ((u >> 16) & 1);  // RNE
  return (unsigned short)(u >> 16);
}
__device__ inline float bf2f(unsigned short h) {
  return __uint_as_float(((unsigned)h) << 16);
}
__device__ inline unsigned short f2h(float x) {
  _Float16 h = (_Float16)x;  // RNE
  return __builtin_bit_cast(unsigned short, h);
}

// ---------------------------------------------------------------------------
// Merged conversions (single dispatch).
// id < 12288 : convert_x — z<2: fp32 -> f16 [4096x1024] (cols [0,1024)).
//              z=2: fp32 -> bf16 split [hi|lo] [4096x2048].
// id >= 12288: convert_w — z<2: W^T f16 single; z>=2: W^T bf16 split.
// ---------------------------------------------------------------------------
__global__ __launch_bounds__(256) void convert_xw(
    const float* __restrict__ x0, const float* __restrict__ x1,
    const float* __restrict__ x2, unsigned short* __restrict__ Xs,
    const float* __restrict__ w0, const float* __restrict__ w1,
    const float* __restrict__ w2, const float* __restrict__ w3,
    unsigned short* __restrict__ Wt) {
  __shared__ float T[64][65];
  const int id = blockIdx.x;
  const int t = threadIdx.x;
  if (id < 12288) {
    int z = id >> 12;
    int bx = id & 4095;
    const float* src = z == 0 ? x0 : (z == 1 ? x1 : x2);
    unsigned short* dst = Xs + (size_t)z * XS_SLAB;
    size_t idx = ((size_t)bx * 256 + t) * 4;
    int r = (int)(idx >> 10);
    int c = (int)(idx & 1023);
    f32x4 v = *(const f32x4*)&src[idx];
    if (z < 2) {
      ushort4 h4 = {f2h(v[0]), f2h(v[1]), f2h(v[2]), f2h(v[3])};
      *(ushort4*)&dst[(size_t)r * 2048 + c] = h4;
    } else {
      unsigned short hi[4], lo[4];
#pragma unroll
      for (int i = 0; i < 4; ++i) {
        float vi = v[i];
        hi[i] = f2bf(vi);
        lo[i] = f2bf(vi - bf2f(hi[i]));
      }
      ushort4 h4 = {hi[0], hi[1], hi[2], hi[3]};
      ushort4 l4 = {lo[0], lo[1], lo[2], lo[3]};
      *(ushort4*)&dst[(size_t)r * 2048 + c] = h4;
      *(ushort4*)&dst[(size_t)r * 2048 + 1024 + c] = l4;
    }
  } else {
    int wid = id - 12288;
    int z = wid >> 8;
    int by = (wid >> 4) & 15;
    int bx = wid & 15;
    const float* W = z == 0 ? w0 : (z == 1 ? w1 : (z == 2 ? w2 : w3));
    unsigned short* dst = Wt + (size_t)z * WT_SLAB;
    int k0 = by * 64, n0 = bx * 64;
#pragma unroll
    for (int i = 0; i < 4; ++i) {
      int row = (t >> 4) + i * 16;
      int c4 = (t & 15) * 4;
      f32x4 v = *(const f32x4*)&W[(size_t)(k0 + row) * 1024 + n0 + c4];
      T[row][c4 + 0] = v[0]; T[row][c4 + 1] = v[1];
      T[row][c4 + 2] = v[2]; T[row][c4 + 3] = v[3];
    }
    __syncthreads();
    int n = t >> 2;
    int kc = (t & 3) * 16;
    unsigned short hi[16], lo[16];
    if (z < 2) {
#pragma unroll
      for (int j = 0; j < 16; ++j) hi[j] = f2h(T[kc + j][n]);
    } else {
#pragma unroll
      for (int j = 0; j < 16; ++j) {
        float x = T[kc + j][n];
        hi[j] = f2bf(x);
        lo[j] = f2bf(x - bf2f(hi[j]));
      }
    }
    size_t base = (size_t)(n0 + n) * 2048 + k0 + kc;
#pragma unroll
    for (int j4 = 0; j4 < 4; ++j4) {
      ushort4 h4 = {hi[j4 * 4], hi[j4 * 4 + 1], hi[j4 * 4 + 2], hi[j4 * 4 + 3]};
      *(ushort4*)&dst[base + j4 * 4] = h4;
      if (z >= 2) {
        ushort4 l4 = {lo[j4 * 4], lo[j4 * 4 + 1], lo[j4 * 4 + 2],
                      lo[j4 * 4 + 3]};
        *(ushort4*)&dst[base + 1024 + j4 * 4] = l4;
      }
    }
  }
}

// ---------------------------------------------------------------------------
// QKV GEMM: C[4096x1024] = A @ W + bias.
// z=0 (Q), z=1 (K): single f16 GEMM, K=1024 (mfma_f32_16x16x32_f16).
// z=2 (V):          bf16x3, K=3072 (A_hi*W_hi + A_hi*W_lo + A_lo*W_hi).
// 128x128 tile, global_load_lds double-buffer, XCD-swizzled block map.
// ---------------------------------------------------------------------------
__global__ __launch_bounds__(256, 3) void gemm_qkv(
    const unsigned short* __restrict__ Abase,
    const unsigned short* __restrict__ Wtbase,
    unsigned short* __restrict__ Cbase, const float* __restrict__ bb0,
    const float* __restrict__ bb1, const float* __restrict__ bb2) {
  __shared__ s16x8 As[2][512];
  __shared__ s16x8 Bs[2][512];
  int z = blockIdx.z;
  const unsigned short* A = Abase + (size_t)z * XS_SLAB;
  const unsigned short* Wt = Wtbase + (size_t)z * WT_SLAB;
  const float* bias = z == 0 ? bb0 : (z == 1 ? bb1 : bb2);
  const float scl = (z == 0) ? 0.125f : 1.0f;
  const int KMAX = (z == 2) ? 3072 : 1024;

  const int t = threadIdx.x;
  const int lane = t & 63, wave = t >> 6;
  const int wm = wave & 1, wn = wave >> 1;

  // XCD swizzle: flat = bn-fast id; XCD c gets bm in [4c, 4c+4) x all bn.
  const int flat = blockIdx.x + (blockIdx.y << 3);          // 0..255
  const int swz = (flat & 7) * 32 + (flat >> 3);
  const int bm = (swz >> 3) * 128, bn = (swz & 7) * 128;

  f32x4 acc[4][4] = {};

  const int s0 = t, s1 = t + 256;
  const int r0 = s0 >> 2, c0 = (s0 & 3) ^ ((r0 >> 1) & 3);
  const int r1 = s1 >> 2, c1 = (s1 & 3) ^ ((r1 >> 1) & 3);
  const unsigned short* A0 = A + (size_t)(bm + r0) * 2048 + c0 * 8;
  const unsigned short* A1 = A + (size_t)(bm + r1) * 2048 + c1 * 8;
  const unsigned short* B0 = Wt + (size_t)(bn + r0) * 2048 + c0 * 8;
  const unsigned short* B1 = Wt + (size_t)(bn + r1) * 2048 + c1 * 8;

  const int m15 = lane & 15, q = lane >> 4;

  gld_lds16(A0, &As[0][wave * 64]);
  gld_lds16(A1, &As[0][256 + wave * 64]);
  gld_lds16(B0, &Bs[0][wave * 64]);
  gld_lds16(B1, &Bs[0][256 + wave * 64]);
  __syncthreads();

  int cur = 0;
  for (int kb = 0; kb < KMAX; kb += 32) {
    const int kn = kb + 32;
    const bool more = (kn < KMAX);
    if (more) {
      // virtual-K segments (z=2): A_hi*W_hi | A_hi*W_lo | A_lo*W_hi.
      // z<2: kn<1024 always -> asrc=wsrc=kn (plain f16 GEMM).
      int asrc = kn < 1024 ? kn : kn - 1024;
      int wsrc = kn < 2048 ? kn : kn - 2048;
      gld_lds16(A0 + asrc, &As[cur ^ 1][wave * 64]);
      gld_lds16(A1 + asrc, &As[cur ^ 1][256 + wave * 64]);
      gld_lds16(B0 + wsrc, &Bs[cur ^ 1][wave * 64]);
      gld_lds16(B1 + wsrc, &Bs[cur ^ 1][256 + wave * 64]);
    }

    if (z == 2) {
      s16x8 af[4], bf[4];
#pragma unroll
      for (int mt = 0; mt < 4; ++mt) {
        int r = wm * 64 + mt * 16 + m15;
        af[mt] = As[cur][r * 4 + (q ^ ((r >> 1) & 3))];
      }
#pragma unroll
      for (int nt = 0; nt < 4; ++nt) {
        int r = wn * 64 + nt * 16 + m15;
        bf[nt] = Bs[cur][r * 4 + (q ^ ((r >> 1) & 3))];
      }
#pragma unroll
      for (int mt = 0; mt < 4; ++mt)
#pragma unroll
        for (int nt = 0; nt < 4; ++nt)
          acc[mt][nt] = __builtin_amdgcn_mfma_f32_16x16x32_bf16(
              af[mt], bf[nt], acc[mt][nt], 0, 0, 0);
    } else {
      const h16x8* AsH = (const h16x8*)As[cur];
      const h16x8* BsH = (const h16x8*)Bs[cur];
      h16x8 af[4], bf[4];
#pragma unroll
      for (int mt = 0; mt < 4; ++mt) {
        int r = wm * 64 + mt * 16 + m15;
        af[mt] = AsH[r * 4 + (q ^ ((r >> 1) & 3))];
      }
#pragma unroll
      for (int nt = 0; nt < 4; ++nt) {
        int r = wn * 64 + nt * 16 + m15;
        bf[nt] = BsH[r * 4 + (q ^ ((r >> 1) & 3))];
      }
#pragma unroll
      for (int mt = 0; mt < 4; ++mt)
#pragma unroll
        for (int nt = 0; nt < 4; ++nt)
          acc[mt][nt] = __builtin_amdgcn_mfma_f32_16x16x32_f16(
              af[mt], bf[nt], acc[mt][nt], 0, 0, 0);
    }

    if (more) {
      __syncthreads();
      cur ^= 1;
    }
  }

#pragma unroll
  for (int nt = 0; nt < 4; ++nt) {
    int col = bn + wn * 64 + nt * 16 + m15;
    float bv = bias[col];
#pragma unroll
    for (int mt = 0; mt < 4; ++mt) {
      int rowb = bm + wm * 64 + mt * 16 + q * 4;
#pragma unroll
      for (int i = 0; i < 4; ++i) {
        float val = (acc[mt][nt][i] + bv) * scl;
        (Cbase + (size_t)z * QB_SLAB)[(size_t)(rowb + i) * 1024 + col] =
            f2bf(val);
      }
    }
  }
}

// ---------------------------------------------------------------------------
// Out-projection GEMM: 64x128 tile, 512 blocks = 2/CU. XCD-swizzled. bf16x3.
// ---------------------------------------------------------------------------
__global__ __launch_bounds__(256, 2) void gemm_out(
    const unsigned short* __restrict__ A,   // XsAO [4096][2048]
    const unsigned short* __restrict__ Wt,  // Wo^T split [1024][2048]
    float* __restrict__ C, const float* __restrict__ bias) {
  __shared__ s16x8 As[2][256];
  __shared__ s16x8 Bs[2][512];
  const int t = threadIdx.x;
  const int lane = t & 63, wave = t >> 6;
  const int wm = wave & 1, wn = wave >> 1;

  const int flat = blockIdx.x + (blockIdx.y << 3);          // 0..511
  const int swz = (flat & 7) * 64 + (flat >> 3);
  const int bm = (swz >> 3) * 64, bn = (swz & 7) * 128;

  f32x4 acc[2][4] = {};

  const int ra = t >> 2, ca = (t & 3) ^ ((ra >> 1) & 3);
  const int s0 = t, s1 = t + 256;
  const int r0 = s0 >> 2, c0 = (s0 & 3) ^ ((r0 >> 1) & 3);
  const int r1 = s1 >> 2, c1 = (s1 & 3) ^ ((r1 >> 1) & 3);
  const unsigned short* Ap = A + (size_t)(bm + ra) * 2048 + ca * 8;
  const unsigned short* B0 = Wt + (size_t)(bn + r0) * 2048 + c0 * 8;
  const unsigned short* B1 = Wt + (size_t)(bn + r1) * 2048 + c1 * 8;

  const int m15 = lane & 15, q = lane >> 4;

  gld_lds16(Ap, &As[0][wave * 64]);
  gld_lds16(B0, &Bs[0][wave * 64]);
  gld_lds16(B1, &Bs[0][256 + wave * 64]);
  __syncthreads();

  int cur = 0;
  for (int kb = 0; kb < 3072; kb += 32) {
    const int kn = kb + 32;
    if (kn < 3072) {
      int asrc = kn < 1024 ? kn : kn - 1024;
      int wsrc = kn < 2048 ? kn : kn - 2048;
      gld_lds16(Ap + asrc, &As[cur ^ 1][wave * 64]);
      gld_lds16(B0 + wsrc, &Bs[cur ^ 1][wave * 64]);
      gld_lds16(B1 + wsrc, &Bs[cur ^ 1][256 + wave * 64]);
    }

    s16x8 af[2], bf[4];
#pragma unroll
    for (int mt = 0; mt < 2; ++mt) {
      int r = wm * 32 + mt * 16 + m15;
      af[mt] = As[cur][r * 4 + (q ^ ((r >> 1) & 3))];
    }
#pragma unroll
    for (int nt = 0; nt < 4; ++nt) {
      int r = wn * 64 + nt * 16 + m15;
      bf[nt] = Bs[cur][r * 4 + (q ^ ((r >> 1) & 3))];
    }
#pragma unroll
    for (int mt = 0; mt < 2; ++mt)
#pragma unroll
      for (int nt = 0; nt < 4; ++nt)
        acc[mt][nt] = __builtin_amdgcn_mfma_f32_16x16x32_bf16(
            af[mt], bf[nt], acc[mt][nt], 0, 0, 0);

    if (kn < 3072) {
      __syncthreads();
      cur ^= 1;
    }
  }

#pragma unroll
  for (int nt = 0; nt < 4; ++nt) {
    int col = bn + wn * 64 + nt * 16 + m15;
    float bv = bias[col];
#pragma unroll
    for (int mt = 0; mt < 2; ++mt) {
      int rowb = bm + wm * 32 + mt * 16 + q * 4;
#pragma unroll
      for (int i = 0; i < 4; ++i) {
        __builtin_nontemporal_store(
            acc[mt][nt][i] + bv, &C[(size_t)(rowb + i) * 1024 + col]);
      }
    }
  }
}

// ---------------------------------------------------------------------------
// Vb [4096][1024] bf16 -> Vt [b][h][d][s] bf16 (per-head transposed).
// ---------------------------------------------------------------------------
__global__ __launch_bounds__(256) void transpose_v(
    const unsigned short* __restrict__ Vb, unsigned short* __restrict__ Vt) {
  __shared__ unsigned short T[64][88];
  const int b = blockIdx.z, h = blockIdx.y, s0 = blockIdx.x * 64;
  const int t = threadIdx.x;
  {
    int row = t >> 2, part = t & 3;
    const unsigned short* src =
        Vb + (size_t)(b * Ss + s0 + row) * 1024 + h * 64 + part * 16;
    s16x8 v0 = *(const s16x8*)src;
    s16x8 v1 = *(const s16x8*)(src + 8);
    *(s16x8*)&T[row][part * 16] = v0;
    *(s16x8*)&T[row][part * 16 + 8] = v1;
  }
  __syncthreads();
  {
    int d = t & 63, sw = t >> 6;
    unsigned short tmp[16];
#pragma unroll
    for (int i = 0; i < 16; ++i) tmp[i] = T[sw * 16 + i][d];
    unsigned short* dst =
        Vt + ((size_t)((b * Hh + h) * 64 + d)) * 2048 + s0 + sw * 16;
    *(s16x8*)dst = *(const s16x8*)&tmp[0];
    *(s16x8*)(dst + 8) = *(const s16x8*)&tmp[8];
  }
}

// ---------------------------------------------------------------------------
// Fused attention v7: per block = one (b,h) x 16-query tile, 4 waves.
// XCD-contiguous swizzle. S1: scores via MFMA -> LDS P (fp32).
// S2: softmax; full-row attn write (band scalar from regs + f32x4 zero fill
// outside the band); bf16 probs overlaid on P row. S3: PV reads bf16 probs.
// ---------------------------------------------------------------------------
constexpr int SW3 = 556;  // f32 stride: 556%32=12 -> <=2-way banks; 16B-aligned
__global__ __launch_bounds__(256) void attn_v7(
    const unsigned short* __restrict__ Qb, const unsigned short* __restrict__ Kb,
    const unsigned short* __restrict__ Vt, float* __restrict__ attn,
    unsigned short* __restrict__ XsAO) {
  __shared__ float P[16 * SW3];  // 35.6 KB
  const int t = threadIdx.x;
  const int lane = t & 63, wave = t >> 6;
  const int m15 = lane & 15, quad = lane >> 4;
  const int bid0 = blockIdx.x;
  const int bid = (bid0 & 7) * 512 + (bid0 >> 3);  // XCD-contiguous (4096=8*512)
  const int qt = bid & 127, h = (bid >> 7) & 15, b = bid >> 11;
  const int q0 = qt * 16;
  int jlo = q0 - WINw; if (jlo < 0) jlo = 0;
  int jhi = q0 + 15 + WINw; if (jhi > Ss - 1) jhi = Ss - 1;
  const int ncols = jhi - jlo + 1;  // multiple of 16, <=528
  const int ntiles = ncols >> 4;

  // ---- stage 1: scores via MFMA -> P (fp32) ----
  {
    const unsigned short* qrow =
        Qb + (size_t)(b * Ss + q0 + m15) * 1024 + h * 64 + quad * 8;
    s16x8 aq0 = *(const s16x8*)qrow;
    s16x8 aq1 = *(const s16x8*)(qrow + 32);
    for (int nt = wave; nt < ntiles; nt += 4) {
      const unsigned short* krow =
          Kb + (size_t)(b * Ss + jlo + nt * 16 + m15) * 1024 + h * 64 + quad * 8;
      s16x8 b0 = *(const s16x8*)krow;
      s16x8 b1 = *(const s16x8*)(krow + 32);
      f32x4 c = {0.f, 0.f, 0.f, 0.f};
      __builtin_amdgcn_s_setprio(1);
      c = __builtin_amdgcn_mfma_f32_16x16x32_bf16(aq0, b0, c, 0, 0, 0);
      c = __builtin_amdgcn_mfma_f32_16x16x32_bf16(aq1, b1, c, 0, 0, 0);
      __builtin_amdgcn_s_setprio(0);
      float* pp = &P[(quad * 4) * SW3 + nt * 16 + m15];
#pragma unroll
      for (int i = 0; i < 4; ++i) pp[i * SW3] = c[i];
    }
  }
  lgkm_barrier();

  // ---- stage 2: softmax; full-row attn write; bf16 probs overlay into P ----
  {
    const f32x4 zv = {0.f, 0.f, 0.f, 0.f};
#pragma unroll
    for (int ri = 0; ri < 4; ++ri) {
      const int r = wave * 4 + ri;
      const int qq = q0 + r;
      int lo = qq - WINw; if (lo < 0) lo = 0;
      int hi = qq + WINw; if (hi > Ss - 1) hi = Ss - 1;
      const int clo = lo - jlo, chi = hi - jlo;
      float sv[9];
      bool ib[9];
      float m = -1e30f;
#pragma unroll
      for (int k2 = 0; k2 < 9; ++k2) {
        int c = k2 * 64 + lane;
        bool inb = (c >= clo) && (c <= chi);
        ib[k2] = inb;
        float vv = inb ? P[r * SW3 + c] : -1e30f;
        sv[k2] = vv;
        m = fmaxf(m, vv);
      }
#pragma unroll
      for (int off = 32; off; off >>= 1) m = fmaxf(m, __shfl_xor(m, off, 64));
      float e[9], l = 0.f;
#pragma unroll
      for (int k2 = 0; k2 < 9; ++k2) { e[k2] = __expf(sv[k2] - m); l += e[k2]; }
#pragma unroll
      for (int off = 32; off; off >>= 1) l += __shfl_xor(l, off, 64);
      const float inv = 1.f / l;
      // overlay: row r's fp32 scores fully consumed into sv[] above
      unsigned short* pb = (unsigned short*)&P[r * SW3];
      float* arow0 = attn + ((size_t)((b * Hh + h) * Ss + qq)) * Ss;
      float* arow = arow0 + jlo;
#pragma unroll
      for (int k2 = 0; k2 < 9; ++k2) {
        int c = k2 * 64 + lane;
        float w = ib[k2] ? e[k2] * inv : 0.f;
        if (c < 544) pb[c] = f2bf(w);
        if (c < ncols) __builtin_nontemporal_store(w, &arow[c]);
      }
      // zero fill outside the band (cols [0,jlo) and [jlo+ncols, 2048))
#pragma unroll
      for (int i = 0; i < 8; ++i) {
        int col = i * 256 + lane * 4;
        if (col < jlo || col >= jlo + ncols)
          __builtin_nontemporal_store(zv, (f32x4*)&arow0[col]);
      }
    }
  }
  lgkm_barrier();

  // ---- stage 3: PV via MFMA; wave = d-tile; A-frags read bf16 from P ----
  {
    const int ntk = (ncols + 31) >> 5;
    const unsigned short* vtrow =
        Vt + ((size_t)((b * Hh + h) * 64 + wave * 16 + m15)) * 2048 + jlo +
        quad * 8;
    f32x4 o = {0.f, 0.f, 0.f, 0.f};
    const unsigned short* pbrow = (const unsigned short*)&P[m15 * SW3];
    for (int ks = 0; ks < ntk; ++ks) {
      s16x8 af = *(const s16x8*)&pbrow[ks * 32 + quad * 8];
      s16x8 bf = *(const s16x8*)(vtrow + ks * 32);
      __builtin_amdgcn_s_setprio(1);
      o = __builtin_amdgcn_mfma_f32_16x16x32_bf16(af, bf, o, 0, 0, 0);
      __builtin_amdgcn_s_setprio(0);
    }
    const int dcol = h * 64 + wave * 16 + m15;
#pragma unroll
    for (int i = 0; i < 4; ++i) {
      int row = q0 + quad * 4 + i;
      unsigned short hi = f2bf(o[i]);
      unsigned short lo = f2bf(o[i] - bf2f(hi));
      unsigned short* dst = XsAO + (size_t)(b * Ss + row) * 2048 + dcol;
      dst[0] = hi;
      dst[1024] = lo;
    }
  }
}

// ---------------------------------------------------------------------------
extern "C" void kernel_launch(void* const* d_in, const int* in_sizes, int n_in,
                              void* d_out, int out_size, void* d_ws,
                              size_t ws_size, hipStream_t stream) {
  const float* q  = (const float*)d_in[0];
  const float* k  = (const float*)d_in[1];
  const float* v  = (const float*)d_in[2];
  const float* Wq = (const float*)d_in[3];
  const float* bq = (const float*)d_in[4];
  const float* Wk = (const float*)d_in[5];
  const float* bk = (const float*)d_in[6];
  const float* Wv = (const float*)d_in[7];
  const float* bv = (const float*)d_in[8];
  const float* Wo = (const float*)d_in[9];
  const float* bo = (const float*)d_in[10];

  float* out = (float*)d_out;
  float* attn = out + (size_t)Bb * Ss * Dd;

  unsigned short* Xs   = (unsigned short*)d_ws;   // 48 MB
  unsigned short* XsAO = Xs + 3 * XS_SLAB;        // 16 MB
  unsigned short* Wt   = XsAO + XS_SLAB;          // 16 MB
  unsigned short* Qb   = Wt + 4 * WT_SLAB;        // 8 MB
  unsigned short* Kb   = Qb + QB_SLAB;            // 8 MB
  unsigned short* Vb   = Kb + QB_SLAB;            // 8 MB
  unsigned short* Vt   = Vb + QB_SLAB;            // 8 MB (+slack after)

  hipLaunchKernelGGL(convert_xw, dim3(12288 + 1024), dim3(256), 0, stream,
                     q, k, v, Xs, Wq, Wk, Wv, Wo, Wt);
  hipLaunchKernelGGL(gemm_qkv, dim3(8, 32, 3), dim3(256), 0, stream,
                     Xs, Wt, Qb, bq, bk, bv);
  hipLaunchKernelGGL(transpose_v, dim3(32, 16, 2), dim3(256), 0, stream,
                     Vb, Vt);
  hipLaunchKernelGGL(attn_v7, dim3(Bb * Hh * (Ss / 16)), dim3(256), 0, stream,
                     Qb, Kb, Vt, attn, XsAO);
  hipLaunchKernelGGL(gemm_out, dim3(8, 64, 1), dim3(256), 0, stream,
                     XsAO, Wt + 3 * WT_SLAB, out, bo);
}

// Round 9
// 683.829 us; speedup vs baseline: 1.3824x; 1.1081x over previous
//
#include <hip/hip_runtime.h>

// B=2, S=2048, D=1024, H=16, d_k=64, WINDOW=256
// d_out = out [B,S,D] fp32  ++  attn [B,H,S,S] fp32
// ws (112 MB): Xs 3x[4096x2048] | XsAO [4096x2048] | Wt 4x[1024x2048]
//              | Qb,Kb,Vb bf16 [4096x1024] | Vt bf16 [B,H,64,2048]
//
// v11: ALL projections (Q,K,V,out) are single f16 GEMMs (K=1024).
// f16 GEMM error (~3.4e-4) is an order of magnitude below the bf16
// Qb/Kb/Vb storage error (~1-2e-3) that already dominates the passing
// absmax (0.0029). This cuts the critical path of gemm_qkv (V leg was
// bf16x3 = 96 K-steps, all blocks co-resident -> leg-bound) and gemm_out
// from 96 to 32 K-steps. Slab strides unchanged; f16 lives in cols [0,1024).

constexpr int Bb = 2, Ss = 2048, Dd = 1024, Hh = 16, WINw = 256;
constexpr size_t XS_SLAB = (size_t)4096 * 2048;  // elems
constexpr size_t WT_SLAB = (size_t)1024 * 2048;  // elems
constexpr size_t QB_SLAB = (size_t)4096 * 1024;  // elems

typedef short s16x8 __attribute__((ext_vector_type(8)));
typedef _Float16 h16x8 __attribute__((ext_vector_type(8)));
typedef float f32x4 __attribute__((ext_vector_type(4)));

typedef __attribute__((address_space(3))) unsigned int lds_uint;
typedef const __attribute__((address_space(1))) unsigned int gbl_uint;

// async global->LDS, 16B per lane; LDS dest = wave-uniform base + lane*16
__device__ __forceinline__ void gld_lds16(const void* g, void* l) {
  __builtin_amdgcn_global_load_lds((gbl_uint*)g, (lds_uint*)l, 16, 0, 0);
}

// LDS-only drain + barrier (lets global stores keep draining across it)
__device__ __forceinline__ void lgkm_barrier() {
  asm volatile("s_waitcnt lgkmcnt(0)" ::: "memory");
  __builtin_amdgcn_s_barrier();
}

__device__ inline unsigned short f2bf(float x) {
  unsigned u = __float_as_uint(x);
  u += 0x7fff + ((u >> 16) & 1);  // RNE
  return (unsigned short)(u >> 16);
}
__device__ inline float bf2f(unsigned short h) {
  return __uint_as_float(((unsigned)h) << 16);
}
__device__ inline unsigned short f2h(float x) {
  _Float16 h = (_Float16)x;  // RNE
  return __builtin_bit_cast(unsigned short, h);
}

// ---------------------------------------------------------------------------
// Merged conversions (single dispatch). All outputs f16.
// id < 12288 : convert_x — fp32 [4096x1024] -> f16, cols [0,1024) of slab.
// id >= 12288: convert_w — W [1024x1024] fp32 -> W^T f16, cols [0,1024).
// ---------------------------------------------------------------------------
__global__ __launch_bounds__(256) void convert_xw(
    const float* __restrict__ x0, const float* __restrict__ x1,
    const float* __restrict__ x2, unsigned short* __restrict__ Xs,
    const float* __restrict__ w0, const float* __restrict__ w1,
    const float* __restrict__ w2, const float* __restrict__ w3,
    unsigned short* __restrict__ Wt) {
  __shared__ float T[64][65];
  const int id = blockIdx.x;
  const int t = threadIdx.x;
  if (id < 12288) {
    int z = id >> 12;
    int bx = id & 4095;
    const float* src = z == 0 ? x0 : (z == 1 ? x1 : x2);
    unsigned short* dst = Xs + (size_t)z * XS_SLAB;
    size_t idx = ((size_t)bx * 256 + t) * 4;
    int r = (int)(idx >> 10);
    int c = (int)(idx & 1023);
    f32x4 v = *(const f32x4*)&src[idx];
    ushort4 h4 = {f2h(v[0]), f2h(v[1]), f2h(v[2]), f2h(v[3])};
    *(ushort4*)&dst[(size_t)r * 2048 + c] = h4;
  } else {
    int wid = id - 12288;
    int z = wid >> 8;
    int by = (wid >> 4) & 15;
    int bx = wid & 15;
    const float* W = z == 0 ? w0 : (z == 1 ? w1 : (z == 2 ? w2 : w3));
    unsigned short* dst = Wt + (size_t)z * WT_SLAB;
    int k0 = by * 64, n0 = bx * 64;
#pragma unroll
    for (int i = 0; i < 4; ++i) {
      int row = (t >> 4) + i * 16;
      int c4 = (t & 15) * 4;
      f32x4 v = *(const f32x4*)&W[(size_t)(k0 + row) * 1024 + n0 + c4];
      T[row][c4 + 0] = v[0]; T[row][c4 + 1] = v[1];
      T[row][c4 + 2] = v[2]; T[row][c4 + 3] = v[3];
    }
    __syncthreads();
    int n = t >> 2;
    int kc = (t & 3) * 16;
    unsigned short hi[16];
#pragma unroll
    for (int j = 0; j < 16; ++j) hi[j] = f2h(T[kc + j][n]);
    size_t base = (size_t)(n0 + n) * 2048 + k0 + kc;
#pragma unroll
    for (int j4 = 0; j4 < 4; ++j4) {
      ushort4 h4 = {hi[j4 * 4], hi[j4 * 4 + 1], hi[j4 * 4 + 2], hi[j4 * 4 + 3]};
      *(ushort4*)&dst[base + j4 * 4] = h4;
    }
  }
}

// ---------------------------------------------------------------------------
// QKV GEMM: C[4096x1024] = f16 A[4096x1024] @ f16 W[1024x1024] + bias.
// All legs (Q,K,V) single f16 GEMM, K=1024 (32 K-steps).
// 128x128 tile, global_load_lds double-buffer, XCD-swizzled block map.
// Output stored bf16 (Qb/Kb/Vb; z=0 scaled 1/8 for attn).
// ---------------------------------------------------------------------------
__global__ __launch_bounds__(256, 3) void gemm_qkv(
    const unsigned short* __restrict__ Abase,
    const unsigned short* __restrict__ Wtbase,
    unsigned short* __restrict__ Cbase, const float* __restrict__ bb0,
    const float* __restrict__ bb1, const float* __restrict__ bb2) {
  __shared__ h16x8 As[2][512];
  __shared__ h16x8 Bs[2][512];
  int z = blockIdx.z;
  const unsigned short* A = Abase + (size_t)z * XS_SLAB;
  const unsigned short* Wt = Wtbase + (size_t)z * WT_SLAB;
  const float* bias = z == 0 ? bb0 : (z == 1 ? bb1 : bb2);
  const float scl = (z == 0) ? 0.125f : 1.0f;

  const int t = threadIdx.x;
  const int lane = t & 63, wave = t >> 6;
  const int wm = wave & 1, wn = wave >> 1;

  // XCD swizzle: flat = bn-fast id; XCD c gets bm in [4c, 4c+4) x all bn.
  const int flat = blockIdx.x + (blockIdx.y << 3);          // 0..255
  const int swz = (flat & 7) * 32 + (flat >> 3);
  const int bm = (swz >> 3) * 128, bn = (swz & 7) * 128;

  f32x4 acc[4][4] = {};

  const int s0 = t, s1 = t + 256;
  const int r0 = s0 >> 2, c0 = (s0 & 3) ^ ((r0 >> 1) & 3);
  const int r1 = s1 >> 2, c1 = (s1 & 3) ^ ((r1 >> 1) & 3);
  const unsigned short* A0 = A + (size_t)(bm + r0) * 2048 + c0 * 8;
  const unsigned short* A1 = A + (size_t)(bm + r1) * 2048 + c1 * 8;
  const unsigned short* B0 = Wt + (size_t)(bn + r0) * 2048 + c0 * 8;
  const unsigned short* B1 = Wt + (size_t)(bn + r1) * 2048 + c1 * 8;

  const int m15 = lane & 15, q = lane >> 4;

  gld_lds16(A0, &As[0][wave * 64]);
  gld_lds16(A1, &As[0][256 + wave * 64]);
  gld_lds16(B0, &Bs[0][wave * 64]);
  gld_lds16(B1, &Bs[0][256 + wave * 64]);
  __syncthreads();

  int cur = 0;
  for (int kb = 0; kb < 1024; kb += 32) {
    const int kn = kb + 32;
    const bool more = (kn < 1024);
    if (more) {
      gld_lds16(A0 + kn, &As[cur ^ 1][wave * 64]);
      gld_lds16(A1 + kn, &As[cur ^ 1][256 + wave * 64]);
      gld_lds16(B0 + kn, &Bs[cur ^ 1][wave * 64]);
      gld_lds16(B1 + kn, &Bs[cur ^ 1][256 + wave * 64]);
    }

    h16x8 af[4], bf[4];
#pragma unroll
    for (int mt = 0; mt < 4; ++mt) {
      int r = wm * 64 + mt * 16 + m15;
      af[mt] = As[cur][r * 4 + (q ^ ((r >> 1) & 3))];
    }
#pragma unroll
    for (int nt = 0; nt < 4; ++nt) {
      int r = wn * 64 + nt * 16 + m15;
      bf[nt] = Bs[cur][r * 4 + (q ^ ((r >> 1) & 3))];
    }
#pragma unroll
    for (int mt = 0; mt < 4; ++mt)
#pragma unroll
      for (int nt = 0; nt < 4; ++nt)
        acc[mt][nt] = __builtin_amdgcn_mfma_f32_16x16x32_f16(
            af[mt], bf[nt], acc[mt][nt], 0, 0, 0);

    if (more) {
      __syncthreads();
      cur ^= 1;
    }
  }

#pragma unroll
  for (int nt = 0; nt < 4; ++nt) {
    int col = bn + wn * 64 + nt * 16 + m15;
    float bv = bias[col];
#pragma unroll
    for (int mt = 0; mt < 4; ++mt) {
      int rowb = bm + wm * 64 + mt * 16 + q * 4;
#pragma unroll
      for (int i = 0; i < 4; ++i) {
        float val = (acc[mt][nt][i] + bv) * scl;
        (Cbase + (size_t)z * QB_SLAB)[(size_t)(rowb + i) * 1024 + col] =
            f2bf(val);
      }
    }
  }
}

// ---------------------------------------------------------------------------
// Out-projection GEMM: f16 single, K=1024. 64x128 tile, 512 blocks = 2/CU.
// A = XsAO f16 (cols [0,1024) of stride-2048 slab), B = Wo^T f16.
// ---------------------------------------------------------------------------
__global__ __launch_bounds__(256, 2) void gemm_out(
    const unsigned short* __restrict__ A,   // XsAO f16 [4096][2048-stride]
    const unsigned short* __restrict__ Wt,  // Wo^T f16 [1024][2048-stride]
    float* __restrict__ C, const float* __restrict__ bias) {
  __shared__ h16x8 As[2][256];
  __shared__ h16x8 Bs[2][512];
  const int t = threadIdx.x;
  const int lane = t & 63, wave = t >> 6;
  const int wm = wave & 1, wn = wave >> 1;

  const int flat = blockIdx.x + (blockIdx.y << 3);          // 0..511
  const int swz = (flat & 7) * 64 + (flat >> 3);
  const int bm = (swz >> 3) * 64, bn = (swz & 7) * 128;

  f32x4 acc[2][4] = {};

  const int ra = t >> 2, ca = (t & 3) ^ ((ra >> 1) & 3);
  const int s0 = t, s1 = t + 256;
  const int r0 = s0 >> 2, c0 = (s0 & 3) ^ ((r0 >> 1) & 3);
  const int r1 = s1 >> 2, c1 = (s1 & 3) ^ ((r1 >> 1) & 3);
  const unsigned short* Ap = A + (size_t)(bm + ra) * 2048 + ca * 8;
  const unsigned short* B0 = Wt + (size_t)(bn + r0) * 2048 + c0 * 8;
  const unsigned short* B1 = Wt + (size_t)(bn + r1) * 2048 + c1 * 8;

  const int m15 = lane & 15, q = lane >> 4;

  gld_lds16(Ap, &As[0][wave * 64]);
  gld_lds16(B0, &Bs[0][wave * 64]);
  gld_lds16(B1, &Bs[0][256 + wave * 64]);
  __syncthreads();

  int cur = 0;
  for (int kb = 0; kb < 1024; kb += 32) {
    const int kn = kb + 32;
    if (kn < 1024) {
      gld_lds16(Ap + kn, &As[cur ^ 1][wave * 64]);
      gld_lds16(B0 + kn, &Bs[cur ^ 1][wave * 64]);
      gld_lds16(B1 + kn, &Bs[cur ^ 1][256 + wave * 64]);
    }

    h16x8 af[2], bf[4];
#pragma unroll
    for (int mt = 0; mt < 2; ++mt) {
      int r = wm * 32 + mt * 16 + m15;
      af[mt] = As[cur][r * 4 + (q ^ ((r >> 1) & 3))];
    }
#pragma unroll
    for (int nt = 0; nt < 4; ++nt) {
      int r = wn * 64 + nt * 16 + m15;
      bf[nt] = Bs[cur][r * 4 + (q ^ ((r >> 1) & 3))];
    }
#pragma unroll
    for (int mt = 0; mt < 2; ++mt)
#pragma unroll
      for (int nt = 0; nt < 4; ++nt)
        acc[mt][nt] = __builtin_amdgcn_mfma_f32_16x16x32_f16(
            af[mt], bf[nt], acc[mt][nt], 0, 0, 0);

    if (kn < 1024) {
      __syncthreads();
      cur ^= 1;
    }
  }

#pragma unroll
  for (int nt = 0; nt < 4; ++nt) {
    int col = bn + wn * 64 + nt * 16 + m15;
    float bv = bias[col];
#pragma unroll
    for (int mt = 0; mt < 2; ++mt) {
      int rowb = bm + wm * 32 + mt * 16 + q * 4;
#pragma unroll
      for (int i = 0; i < 4; ++i) {
        __builtin_nontemporal_store(
            acc[mt][nt][i] + bv, &C[(size_t)(rowb + i) * 1024 + col]);
      }
    }
  }
}

// ---------------------------------------------------------------------------
// Vb [4096][1024] bf16 -> Vt [b][h][d][s] bf16 (per-head transposed).
// ---------------------------------------------------------------------------
__global__ __launch_bounds__(256) void transpose_v(
    const unsigned short* __restrict__ Vb, unsigned short* __restrict__ Vt) {
  __shared__ unsigned short T[64][88];
  const int b = blockIdx.z, h = blockIdx.y, s0 = blockIdx.x * 64;
  const int t = threadIdx.x;
  {
    int row = t >> 2, part = t & 3;
    const unsigned short* src =
        Vb + (size_t)(b * Ss + s0 + row) * 1024 + h * 64 + part * 16;
    s16x8 v0 = *(const s16x8*)src;
    s16x8 v1 = *(const s16x8*)(src + 8);
    *(s16x8*)&T[row][part * 16] = v0;
    *(s16x8*)&T[row][part * 16 + 8] = v1;
  }
  __syncthreads();
  {
    int d = t & 63, sw = t >> 6;
    unsigned short tmp[16];
#pragma unroll
    for (int i = 0; i < 16; ++i) tmp[i] = T[sw * 16 + i][d];
    unsigned short* dst =
        Vt + ((size_t)((b * Hh + h) * 64 + d)) * 2048 + s0 + sw * 16;
    *(s16x8*)dst = *(const s16x8*)&tmp[0];
    *(s16x8*)(dst + 8) = *(const s16x8*)&tmp[8];
  }
}

// ---------------------------------------------------------------------------
// Fused attention v8: per block = one (b,h) x 16-query tile, 4 waves.
// XCD-contiguous swizzle. S1: scores via MFMA -> LDS P (fp32).
// S2: softmax; full-row attn write (band from regs + f32x4 zero fill);
// bf16 probs overlaid on P row. S3: PV; epilogue writes AO as f16 single.
// ---------------------------------------------------------------------------
constexpr int SW3 = 556;  // f32 stride: 556%32=12 -> <=2-way banks; 16B-aligned
__global__ __launch_bounds__(256) void attn_v8(
    const unsigned short* __restrict__ Qb, const unsigned short* __restrict__ Kb,
    const unsigned short* __restrict__ Vt, float* __restrict__ attn,
    unsigned short* __restrict__ XsAO) {
  __shared__ float P[16 * SW3];  // 35.6 KB
  const int t = threadIdx.x;
  const int lane = t & 63, wave = t >> 6;
  const int m15 = lane & 15, quad = lane >> 4;
  const int bid0 = blockIdx.x;
  const int bid = (bid0 & 7) * 512 + (bid0 >> 3);  // XCD-contiguous (4096=8*512)
  const int qt = bid & 127, h = (bid >> 7) & 15, b = bid >> 11;
  const int q0 = qt * 16;
  int jlo = q0 - WINw; if (jlo < 0) jlo = 0;
  int jhi = q0 + 15 + WINw; if (jhi > Ss - 1) jhi = Ss - 1;
  const int ncols = jhi - jlo + 1;  // multiple of 16, <=528
  const int ntiles = ncols >> 4;

  // ---- stage 1: scores via MFMA -> P (fp32) ----
  {
    const unsigned short* qrow =
        Qb + (size_t)(b * Ss + q0 + m15) * 1024 + h * 64 + quad * 8;
    s16x8 aq0 = *(const s16x8*)qrow;
    s16x8 aq1 = *(const s16x8*)(qrow + 32);
    for (int nt = wave; nt < ntiles; nt += 4) {
      const unsigned short* krow =
          Kb + (size_t)(b * Ss + jlo + nt * 16 + m15) * 1024 + h * 64 + quad * 8;
      s16x8 b0 = *(const s16x8*)krow;
      s16x8 b1 = *(const s16x8*)(krow + 32);
      f32x4 c = {0.f, 0.f, 0.f, 0.f};
      __builtin_amdgcn_s_setprio(1);
      c = __builtin_amdgcn_mfma_f32_16x16x32_bf16(aq0, b0, c, 0, 0, 0);
      c = __builtin_amdgcn_mfma_f32_16x16x32_bf16(aq1, b1, c, 0, 0, 0);
      __builtin_amdgcn_s_setprio(0);
      float* pp = &P[(quad * 4) * SW3 + nt * 16 + m15];
#pragma unroll
      for (int i = 0; i < 4; ++i) pp[i * SW3] = c[i];
    }
  }
  lgkm_barrier();

  // ---- stage 2: softmax; full-row attn write; bf16 probs overlay into P ----
  {
    const f32x4 zv = {0.f, 0.f, 0.f, 0.f};
#pragma unroll
    for (int ri = 0; ri < 4; ++ri) {
      const int r = wave * 4 + ri;
      const int qq = q0 + r;
      int lo = qq - WINw; if (lo < 0) lo = 0;
      int hi = qq + WINw; if (hi > Ss - 1) hi = Ss - 1;
      const int clo = lo - jlo, chi = hi - jlo;
      float sv[9];
      bool ib[9];
      float m = -1e30f;
#pragma unroll
      for (int k2 = 0; k2 < 9; ++k2) {
        int c = k2 * 64 + lane;
        bool inb = (c >= clo) && (c <= chi);
        ib[k2] = inb;
        float vv = inb ? P[r * SW3 + c] : -1e30f;
        sv[k2] = vv;
        m = fmaxf(m, vv);
      }
#pragma unroll
      for (int off = 32; off; off >>= 1) m = fmaxf(m, __shfl_xor(m, off, 64));
      float e[9], l = 0.f;
#pragma unroll
      for (int k2 = 0; k2 < 9; ++k2) { e[k2] = __expf(sv[k2] - m); l += e[k2]; }
#pragma unroll
      for (int off = 32; off; off >>= 1) l += __shfl_xor(l, off, 64);
      const float inv = 1.f / l;
      // overlay: row r's fp32 scores fully consumed into sv[] above
      unsigned short* pb = (unsigned short*)&P[r * SW3];
      float* arow0 = attn + ((size_t)((b * Hh + h) * Ss + qq)) * Ss;
      float* arow = arow0 + jlo;
#pragma unroll
      for (int k2 = 0; k2 < 9; ++k2) {
        int c = k2 * 64 + lane;
        float w = ib[k2] ? e[k2] * inv : 0.f;
        if (c < 544) pb[c] = f2bf(w);
        if (c < ncols) __builtin_nontemporal_store(w, &arow[c]);
      }
      // zero fill outside the band (cols [0,jlo) and [jlo+ncols, 2048))
#pragma unroll
      for (int i = 0; i < 8; ++i) {
        int col = i * 256 + lane * 4;
        if (col < jlo || col >= jlo + ncols)
          __builtin_nontemporal_store(zv, (f32x4*)&arow0[col]);
      }
    }
  }
  lgkm_barrier();

  // ---- stage 3: PV via MFMA; wave = d-tile; A-frags read bf16 from P ----
  {
    const int ntk = (ncols + 31) >> 5;
    const unsigned short* vtrow =
        Vt + ((size_t)((b * Hh + h) * 64 + wave * 16 + m15)) * 2048 + jlo +
        quad * 8;
    f32x4 o = {0.f, 0.f, 0.f, 0.f};
    const unsigned short* pbrow = (const unsigned short*)&P[m15 * SW3];
    for (int ks = 0; ks < ntk; ++ks) {
      s16x8 af = *(const s16x8*)&pbrow[ks * 32 + quad * 8];
      s16x8 bf = *(const s16x8*)(vtrow + ks * 32);
      __builtin_amdgcn_s_setprio(1);
      o = __builtin_amdgcn_mfma_f32_16x16x32_bf16(af, bf, o, 0, 0, 0);
      __builtin_amdgcn_s_setprio(0);
    }
    const int dcol = h * 64 + wave * 16 + m15;
#pragma unroll
    for (int i = 0; i < 4; ++i) {
      int row = q0 + quad * 4 + i;
      XsAO[(size_t)(b * Ss + row) * 2048 + dcol] = f2h(o[i]);
    }
  }
}

// ---------------------------------------------------------------------------
extern "C" void kernel_launch(void* const* d_in, const int* in_sizes, int n_in,
                              void* d_out, int out_size, void* d_ws,
                              size_t ws_size, hipStream_t stream) {
  const float* q  = (const float*)d_in[0];
  const float* k  = (const float*)d_in[1];
  const float* v  = (const float*)d_in[2];
  const float* Wq = (const float*)d_in[3];
  const float* bq = (const float*)d_in[4];
  const float* Wk = (const float*)d_in[5];
  const float* bk = (const float*)d_in[6];
  const float* Wv = (const float*)d_in[7];
  const float* bv = (const float*)d_in[8];
  const float* Wo = (const float*)d_in[9];
  const float* bo = (const float*)d_in[10];

  float* out = (float*)d_out;
  float* attn = out + (size_t)Bb * Ss * Dd;

  unsigned short* Xs   = (unsigned short*)d_ws;   // 48 MB
  unsigned short* XsAO = Xs + 3 * XS_SLAB;        // 16 MB
  unsigned short* Wt   = XsAO + XS_SLAB;          // 16 MB
  unsigned short* Qb   = Wt + 4 * WT_SLAB;        // 8 MB
  unsigned short* Kb   = Qb + QB_SLAB;            // 8 MB
  unsigned short* Vb   = Kb + QB_SLAB;            // 8 MB
  unsigned short* Vt   = Vb + QB_SLAB;            // 8 MB (+slack after)

  hipLaunchKernelGGL(convert_xw, dim3(12288 + 1024), dim3(256), 0, stream,
                     q, k, v, Xs, Wq, Wk, Wv, Wo, Wt);
  hipLaunchKernelGGL(gemm_qkv, dim3(8, 32, 3), dim3(256), 0, stream,
                     Xs, Wt, Qb, bq, bk, bv);
  hipLaunchKernelGGL(transpose_v, dim3(32, 16, 2), dim3(256), 0, stream,
                     Vb, Vt);
  hipLaunchKernelGGL(attn_v8, dim3(Bb * Hh * (Ss / 16)), dim3(256), 0, stream,
                     Qb, Kb, Vt, attn, XsAO);
  hipLaunchKernelGGL(gemm_out, dim3(8, 64, 1), dim3(256), 0, stream,
                     XsAO, Wt + 3 * WT_SLAB, out, bo);
}

// Round 10
// 674.327 us; speedup vs baseline: 1.4019x; 1.0141x over previous
//
#include <hip/hip_runtime.h>

// B=2, S=2048, D=1024, H=16, d_k=64, WINDOW=256
// d_out = out [B,S,D] fp32  ++  attn [B,H,S,S] fp32
// ws (112 MB): Xs 3x[4096x2048] | XsAO [4096x2048] | Wt 4x[1024x2048]
//              | Qb,Kb f16 [4096x1024] | (Vb unused) | Vt f16 [B,H,64,2048]
//
// v12: (a) transpose_v is FUSED into gemm_qkv's z=2 epilogue (V written
// directly in [b][h][d][s] layout; Vb dead; one fewer dispatch).
// (b) Q/K/V/probs storage is f16 (was bf16) — same bytes/rate, 8x lower
// storage error (the dominant absmax term). All attn MFMAs are f16.

constexpr int Bb = 2, Ss = 2048, Dd = 1024, Hh = 16, WINw = 256;
constexpr size_t XS_SLAB = (size_t)4096 * 2048;  // elems
constexpr size_t WT_SLAB = (size_t)1024 * 2048;  // elems
constexpr size_t QB_SLAB = (size_t)4096 * 1024;  // elems

typedef short s16x8 __attribute__((ext_vector_type(8)));
typedef _Float16 h16x8 __attribute__((ext_vector_type(8)));
typedef float f32x4 __attribute__((ext_vector_type(4)));

typedef __attribute__((address_space(3))) unsigned int lds_uint;
typedef const __attribute__((address_space(1))) unsigned int gbl_uint;

// async global->LDS, 16B per lane; LDS dest = wave-uniform base + lane*16
__device__ __forceinline__ void gld_lds16(const void* g, void* l) {
  __builtin_amdgcn_global_load_lds((gbl_uint*)g, (lds_uint*)l, 16, 0, 0);
}

// LDS-only drain + barrier (lets global stores keep draining across it)
__device__ __forceinline__ void lgkm_barrier() {
  asm volatile("s_waitcnt lgkmcnt(0)" ::: "memory");
  __builtin_amdgcn_s_barrier();
}

__device__ inline unsigned short f2bf(float x) {
  unsigned u = __float_as_uint(x);
  u += 0x7fff + ((u >> 16) & 1);  // RNE
  return (unsigned short)(u >> 16);
}
__device__ inline unsigned short f2h(float x) {
  _Float16 h = (_Float16)x;  // RNE
  return __builtin_bit_cast(unsigned short, h);
}

// ---------------------------------------------------------------------------
// Merged conversions (single dispatch). All outputs f16.
// id < 12288 : convert_x — fp32 [4096x1024] -> f16, cols [0,1024) of slab.
// id >= 12288: convert_w — W [1024x1024] fp32 -> W^T f16, cols [0,1024).
// ---------------------------------------------------------------------------
__global__ __launch_bounds__(256) void convert_xw(
    const float* __restrict__ x0, const float* __restrict__ x1,
    const float* __restrict__ x2, unsigned short* __restrict__ Xs,
    const float* __restrict__ w0, const float* __restrict__ w1,
    const float* __restrict__ w2, const float* __restrict__ w3,
    unsigned short* __restrict__ Wt) {
  __shared__ float T[64][65];
  const int id = blockIdx.x;
  const int t = threadIdx.x;
  if (id < 12288) {
    int z = id >> 12;
    int bx = id & 4095;
    const float* src = z == 0 ? x0 : (z == 1 ? x1 : x2);
    unsigned short* dst = Xs + (size_t)z * XS_SLAB;
    size_t idx = ((size_t)bx * 256 + t) * 4;
    int r = (int)(idx >> 10);
    int c = (int)(idx & 1023);
    f32x4 v = *(const f32x4*)&src[idx];
    ushort4 h4 = {f2h(v[0]), f2h(v[1]), f2h(v[2]), f2h(v[3])};
    *(ushort4*)&dst[(size_t)r * 2048 + c] = h4;
  } else {
    int wid = id - 12288;
    int z = wid >> 8;
    int by = (wid >> 4) & 15;
    int bx = wid & 15;
    const float* W = z == 0 ? w0 : (z == 1 ? w1 : (z == 2 ? w2 : w3));
    unsigned short* dst = Wt + (size_t)z * WT_SLAB;
    int k0 = by * 64, n0 = bx * 64;
#pragma unroll
    for (int i = 0; i < 4; ++i) {
      int row = (t >> 4) + i * 16;
      int c4 = (t & 15) * 4;
      f32x4 v = *(const f32x4*)&W[(size_t)(k0 + row) * 1024 + n0 + c4];
      T[row][c4 + 0] = v[0]; T[row][c4 + 1] = v[1];
      T[row][c4 + 2] = v[2]; T[row][c4 + 3] = v[3];
    }
    __syncthreads();
    int n = t >> 2;
    int kc = (t & 3) * 16;
    unsigned short hi[16];
#pragma unroll
    for (int j = 0; j < 16; ++j) hi[j] = f2h(T[kc + j][n]);
    size_t base = (size_t)(n0 + n) * 2048 + k0 + kc;
#pragma unroll
    for (int j4 = 0; j4 < 4; ++j4) {
      ushort4 h4 = {hi[j4 * 4], hi[j4 * 4 + 1], hi[j4 * 4 + 2], hi[j4 * 4 + 3]};
      *(ushort4*)&dst[base + j4 * 4] = h4;
    }
  }
}

// ---------------------------------------------------------------------------
// QKV GEMM: C[4096x1024] = f16 A @ f16 W + bias, K=1024 (32 K-steps).
// z=0 (Q), z=1 (K): row-major f16 out (Qb/Kb; z=0 scaled 1/8).
// z=2 (V): epilogue writes Vt [b][h][d][s] f16 DIRECTLY (fused transpose);
//          per (nt,mt): 4 consecutive s -> one 8B packed store per lane.
// 128x128 tile, global_load_lds double-buffer, XCD-swizzled block map.
// ---------------------------------------------------------------------------
__global__ __launch_bounds__(256, 3) void gemm_qkv(
    const unsigned short* __restrict__ Abase,
    const unsigned short* __restrict__ Wtbase,
    unsigned short* __restrict__ Cbase, unsigned short* __restrict__ Vt,
    const float* __restrict__ bb0, const float* __restrict__ bb1,
    const float* __restrict__ bb2) {
  __shared__ h16x8 As[2][512];
  __shared__ h16x8 Bs[2][512];
  int z = blockIdx.z;
  const unsigned short* A = Abase + (size_t)z * XS_SLAB;
  const unsigned short* Wt = Wtbase + (size_t)z * WT_SLAB;
  const float* bias = z == 0 ? bb0 : (z == 1 ? bb1 : bb2);
  const float scl = (z == 0) ? 0.125f : 1.0f;

  const int t = threadIdx.x;
  const int lane = t & 63, wave = t >> 6;
  const int wm = wave & 1, wn = wave >> 1;

  // XCD swizzle: flat = bn-fast id; XCD c gets bm in [4c, 4c+4) x all bn.
  const int flat = blockIdx.x + (blockIdx.y << 3);          // 0..255
  const int swz = (flat & 7) * 32 + (flat >> 3);
  const int bm = (swz >> 3) * 128, bn = (swz & 7) * 128;

  f32x4 acc[4][4] = {};

  const int s0 = t, s1 = t + 256;
  const int r0 = s0 >> 2, c0 = (s0 & 3) ^ ((r0 >> 1) & 3);
  const int r1 = s1 >> 2, c1 = (s1 & 3) ^ ((r1 >> 1) & 3);
  const unsigned short* A0 = A + (size_t)(bm + r0) * 2048 + c0 * 8;
  const unsigned short* A1 = A + (size_t)(bm + r1) * 2048 + c1 * 8;
  const unsigned short* B0 = Wt + (size_t)(bn + r0) * 2048 + c0 * 8;
  const unsigned short* B1 = Wt + (size_t)(bn + r1) * 2048 + c1 * 8;

  const int m15 = lane & 15, q = lane >> 4;

  gld_lds16(A0, &As[0][wave * 64]);
  gld_lds16(A1, &As[0][256 + wave * 64]);
  gld_lds16(B0, &Bs[0][wave * 64]);
  gld_lds16(B1, &Bs[0][256 + wave * 64]);
  __syncthreads();

  int cur = 0;
  for (int kb = 0; kb < 1024; kb += 32) {
    const int kn = kb + 32;
    const bool more = (kn < 1024);
    if (more) {
      gld_lds16(A0 + kn, &As[cur ^ 1][wave * 64]);
      gld_lds16(A1 + kn, &As[cur ^ 1][256 + wave * 64]);
      gld_lds16(B0 + kn, &Bs[cur ^ 1][wave * 64]);
      gld_lds16(B1 + kn, &Bs[cur ^ 1][256 + wave * 64]);
    }

    h16x8 af[4], bf[4];
#pragma unroll
    for (int mt = 0; mt < 4; ++mt) {
      int r = wm * 64 + mt * 16 + m15;
      af[mt] = As[cur][r * 4 + (q ^ ((r >> 1) & 3))];
    }
#pragma unroll
    for (int nt = 0; nt < 4; ++nt) {
      int r = wn * 64 + nt * 16 + m15;
      bf[nt] = Bs[cur][r * 4 + (q ^ ((r >> 1) & 3))];
    }
#pragma unroll
    for (int mt = 0; mt < 4; ++mt)
#pragma unroll
      for (int nt = 0; nt < 4; ++nt)
        acc[mt][nt] = __builtin_amdgcn_mfma_f32_16x16x32_f16(
            af[mt], bf[nt], acc[mt][nt], 0, 0, 0);

    if (more) {
      __syncthreads();
      cur ^= 1;
    }
  }

  if (z < 2) {
#pragma unroll
    for (int nt = 0; nt < 4; ++nt) {
      int col = bn + wn * 64 + nt * 16 + m15;
      float bv = bias[col];
#pragma unroll
      for (int mt = 0; mt < 4; ++mt) {
        int rowb = bm + wm * 64 + mt * 16 + q * 4;
#pragma unroll
        for (int i = 0; i < 4; ++i) {
          float val = (acc[mt][nt][i] + bv) * scl;
          (Cbase + (size_t)z * QB_SLAB)[(size_t)(rowb + i) * 1024 + col] =
              f2h(val);
        }
      }
    }
  } else {
    // fused transpose: write Vt[b][h][d][s]; row=(b*2048+s), col=(h*64+d).
#pragma unroll
    for (int nt = 0; nt < 4; ++nt) {
      int col = bn + wn * 64 + nt * 16 + m15;
      float bv = bias[col];
      int hh = col >> 6, d = col & 63;
#pragma unroll
      for (int mt = 0; mt < 4; ++mt) {
        int rowb = bm + wm * 64 + mt * 16 + q * 4;
        int b_ = rowb >> 11, s = rowb & 2047;  // 4 consecutive s
        ushort4 pk = {f2h(acc[mt][nt][0] + bv), f2h(acc[mt][nt][1] + bv),
                      f2h(acc[mt][nt][2] + bv), f2h(acc[mt][nt][3] + bv)};
        *(ushort4*)&Vt[((size_t)((b_ * Hh + hh) * 64 + d)) * 2048 + s] = pk;
      }
    }
  }
}

// ---------------------------------------------------------------------------
// Out-projection GEMM: f16 single, K=1024. 64x128 tile, 512 blocks = 2/CU.
// ---------------------------------------------------------------------------
__global__ __launch_bounds__(256, 2) void gemm_out(
    const unsigned short* __restrict__ A,   // XsAO f16 [4096][2048-stride]
    const unsigned short* __restrict__ Wt,  // Wo^T f16 [1024][2048-stride]
    float* __restrict__ C, const float* __restrict__ bias) {
  __shared__ h16x8 As[2][256];
  __shared__ h16x8 Bs[2][512];
  const int t = threadIdx.x;
  const int lane = t & 63, wave = t >> 6;
  const int wm = wave & 1, wn = wave >> 1;

  const int flat = blockIdx.x + (blockIdx.y << 3);          // 0..511
  const int swz = (flat & 7) * 64 + (flat >> 3);
  const int bm = (swz >> 3) * 64, bn = (swz & 7) * 128;

  f32x4 acc[2][4] = {};

  const int ra = t >> 2, ca = (t & 3) ^ ((ra >> 1) & 3);
  const int s0 = t, s1 = t + 256;
  const int r0 = s0 >> 2, c0 = (s0 & 3) ^ ((r0 >> 1) & 3);
  const int r1 = s1 >> 2, c1 = (s1 & 3) ^ ((r1 >> 1) & 3);
  const unsigned short* Ap = A + (size_t)(bm + ra) * 2048 + ca * 8;
  const unsigned short* B0 = Wt + (size_t)(bn + r0) * 2048 + c0 * 8;
  const unsigned short* B1 = Wt + (size_t)(bn + r1) * 2048 + c1 * 8;

  const int m15 = lane & 15, q = lane >> 4;

  gld_lds16(Ap, &As[0][wave * 64]);
  gld_lds16(B0, &Bs[0][wave * 64]);
  gld_lds16(B1, &Bs[0][256 + wave * 64]);
  __syncthreads();

  int cur = 0;
  for (int kb = 0; kb < 1024; kb += 32) {
    const int kn = kb + 32;
    if (kn < 1024) {
      gld_lds16(Ap + kn, &As[cur ^ 1][wave * 64]);
      gld_lds16(B0 + kn, &Bs[cur ^ 1][wave * 64]);
      gld_lds16(B1 + kn, &Bs[cur ^ 1][256 + wave * 64]);
    }

    h16x8 af[2], bf[4];
#pragma unroll
    for (int mt = 0; mt < 2; ++mt) {
      int r = wm * 32 + mt * 16 + m15;
      af[mt] = As[cur][r * 4 + (q ^ ((r >> 1) & 3))];
    }
#pragma unroll
    for (int nt = 0; nt < 4; ++nt) {
      int r = wn * 64 + nt * 16 + m15;
      bf[nt] = Bs[cur][r * 4 + (q ^ ((r >> 1) & 3))];
    }
#pragma unroll
    for (int mt = 0; mt < 2; ++mt)
#pragma unroll
      for (int nt = 0; nt < 4; ++nt)
        acc[mt][nt] = __builtin_amdgcn_mfma_f32_16x16x32_f16(
            af[mt], bf[nt], acc[mt][nt], 0, 0, 0);

    if (kn < 1024) {
      __syncthreads();
      cur ^= 1;
    }
  }

#pragma unroll
  for (int nt = 0; nt < 4; ++nt) {
    int col = bn + wn * 64 + nt * 16 + m15;
    float bv = bias[col];
#pragma unroll
    for (int mt = 0; mt < 2; ++mt) {
      int rowb = bm + wm * 32 + mt * 16 + q * 4;
#pragma unroll
      for (int i = 0; i < 4; ++i) {
        __builtin_nontemporal_store(
            acc[mt][nt][i] + bv, &C[(size_t)(rowb + i) * 1024 + col]);
      }
    }
  }
}

// ---------------------------------------------------------------------------
// Fused attention v9 (all-f16 operand path): per block = (b,h) x 16 queries.
// XCD-contiguous swizzle. S1: scores f16 MFMA -> LDS P (fp32).
// S2: softmax; full-row attn write (band from regs + f32x4 zero fill);
// f16 probs overlaid on P row. S3: PV f16 MFMA; epilogue writes AO f16.
// ---------------------------------------------------------------------------
constexpr int SW3 = 556;  // f32 stride: 556%32=12 -> <=2-way banks; 16B-aligned
__global__ __launch_bounds__(256) void attn_v9(
    const unsigned short* __restrict__ Qb, const unsigned short* __restrict__ Kb,
    const unsigned short* __restrict__ Vt, float* __restrict__ attn,
    unsigned short* __restrict__ XsAO) {
  __shared__ float P[16 * SW3];  // 35.6 KB
  const int t = threadIdx.x;
  const int lane = t & 63, wave = t >> 6;
  const int m15 = lane & 15, quad = lane >> 4;
  const int bid0 = blockIdx.x;
  const int bid = (bid0 & 7) * 512 + (bid0 >> 3);  // XCD-contiguous (4096=8*512)
  const int qt = bid & 127, h = (bid >> 7) & 15, b = bid >> 11;
  const int q0 = qt * 16;
  int jlo = q0 - WINw; if (jlo < 0) jlo = 0;
  int jhi = q0 + 15 + WINw; if (jhi > Ss - 1) jhi = Ss - 1;
  const int ncols = jhi - jlo + 1;  // multiple of 16, <=528
  const int ntiles = ncols >> 4;

  // ---- stage 1: scores via f16 MFMA -> P (fp32) ----
  {
    const unsigned short* qrow =
        Qb + (size_t)(b * Ss + q0 + m15) * 1024 + h * 64 + quad * 8;
    h16x8 aq0 = *(const h16x8*)qrow;
    h16x8 aq1 = *(const h16x8*)(qrow + 32);
    for (int nt = wave; nt < ntiles; nt += 4) {
      const unsigned short* krow =
          Kb + (size_t)(b * Ss + jlo + nt * 16 + m15) * 1024 + h * 64 + quad * 8;
      h16x8 b0 = *(const h16x8*)krow;
      h16x8 b1 = *(const h16x8*)(krow + 32);
      f32x4 c = {0.f, 0.f, 0.f, 0.f};
      __builtin_amdgcn_s_setprio(1);
      c = __builtin_amdgcn_mfma_f32_16x16x32_f16(aq0, b0, c, 0, 0, 0);
      c = __builtin_amdgcn_mfma_f32_16x16x32_f16(aq1, b1, c, 0, 0, 0);
      __builtin_amdgcn_s_setprio(0);
      float* pp = &P[(quad * 4) * SW3 + nt * 16 + m15];
#pragma unroll
      for (int i = 0; i < 4; ++i) pp[i * SW3] = c[i];
    }
  }
  lgkm_barrier();

  // ---- stage 2: softmax; full-row attn write; f16 probs overlay into P ----
  {
    const f32x4 zv = {0.f, 0.f, 0.f, 0.f};
#pragma unroll
    for (int ri = 0; ri < 4; ++ri) {
      const int r = wave * 4 + ri;
      const int qq = q0 + r;
      int lo = qq - WINw; if (lo < 0) lo = 0;
      int hi = qq + WINw; if (hi > Ss - 1) hi = Ss - 1;
      const int clo = lo - jlo, chi = hi - jlo;
      float sv[9];
      bool ib[9];
      float m = -1e30f;
#pragma unroll
      for (int k2 = 0; k2 < 9; ++k2) {
        int c = k2 * 64 + lane;
        bool inb = (c >= clo) && (c <= chi);
        ib[k2] = inb;
        float vv = inb ? P[r * SW3 + c] : -1e30f;
        sv[k2] = vv;
        m = fmaxf(m, vv);
      }
#pragma unroll
      for (int off = 32; off; off >>= 1) m = fmaxf(m, __shfl_xor(m, off, 64));
      float e[9], l = 0.f;
#pragma unroll
      for (int k2 = 0; k2 < 9; ++k2) { e[k2] = __expf(sv[k2] - m); l += e[k2]; }
#pragma unroll
      for (int off = 32; off; off >>= 1) l += __shfl_xor(l, off, 64);
      const float inv = 1.f / l;
      // overlay: row r's fp32 scores fully consumed into sv[] above
      unsigned short* pb = (unsigned short*)&P[r * SW3];
      float* arow0 = attn + ((size_t)((b * Hh + h) * Ss + qq)) * Ss;
      float* arow = arow0 + jlo;
#pragma unroll
      for (int k2 = 0; k2 < 9; ++k2) {
        int c = k2 * 64 + lane;
        float w = ib[k2] ? e[k2] * inv : 0.f;
        if (c < 544) pb[c] = f2h(w);
        if (c < ncols) __builtin_nontemporal_store(w, &arow[c]);
      }
      // zero fill outside the band (cols [0,jlo) and [jlo+ncols, 2048))
#pragma unroll
      for (int i = 0; i < 8; ++i) {
        int col = i * 256 + lane * 4;
        if (col < jlo || col >= jlo + ncols)
          __builtin_nontemporal_store(zv, (f32x4*)&arow0[col]);
      }
    }
  }
  lgkm_barrier();

  // ---- stage 3: PV via f16 MFMA; wave = d-tile; A-frags read f16 from P ----
  {
    const int ntk = (ncols + 31) >> 5;
    const unsigned short* vtrow =
        Vt + ((size_t)((b * Hh + h) * 64 + wave * 16 + m15)) * 2048 + jlo +
        quad * 8;
    f32x4 o = {0.f, 0.f, 0.f, 0.f};
    const unsigned short* pbrow = (const unsigned short*)&P[m15 * SW3];
    for (int ks = 0; ks < ntk; ++ks) {
      h16x8 af = *(const h16x8*)&pbrow[ks * 32 + quad * 8];
      h16x8 bf = *(const h16x8*)(vtrow + ks * 32);
      __builtin_amdgcn_s_setprio(1);
      o = __builtin_amdgcn_mfma_f32_16x16x32_f16(af, bf, o, 0, 0, 0);
      __builtin_amdgcn_s_setprio(0);
    }
    const int dcol = h * 64 + wave * 16 + m15;
#pragma unroll
    for (int i = 0; i < 4; ++i) {
      int row = q0 + quad * 4 + i;
      XsAO[(size_t)(b * Ss + row) * 2048 + dcol] = f2h(o[i]);
    }
  }
}

// ---------------------------------------------------------------------------
extern "C" void kernel_launch(void* const* d_in, const int* in_sizes, int n_in,
                              void* d_out, int out_size, void* d_ws,
                              size_t ws_size, hipStream_t stream) {
  const float* q  = (const float*)d_in[0];
  const float* k  = (const float*)d_in[1];
  const float* v  = (const float*)d_in[2];
  const float* Wq = (const float*)d_in[3];
  const float* bq = (const float*)d_in[4];
  const float* Wk = (const float*)d_in[5];
  const float* bk = (const float*)d_in[6];
  const float* Wv = (const float*)d_in[7];
  const float* bv = (const float*)d_in[8];
  const float* Wo = (const float*)d_in[9];
  const float* bo = (const float*)d_in[10];

  float* out = (float*)d_out;
  float* attn = out + (size_t)Bb * Ss * Dd;

  unsigned short* Xs   = (unsigned short*)d_ws;   // 48 MB
  unsigned short* XsAO = Xs + 3 * XS_SLAB;        // 16 MB
  unsigned short* Wt   = XsAO + XS_SLAB;          // 16 MB
  unsigned short* Qb   = Wt + 4 * WT_SLAB;        // 8 MB
  unsigned short* Kb   = Qb + QB_SLAB;            // 8 MB
  unsigned short* Vb   = Kb + QB_SLAB;            // 8 MB (unused, layout kept)
  unsigned short* Vt   = Vb + QB_SLAB;            // 8 MB (+slack after)

  hipLaunchKernelGGL(convert_xw, dim3(12288 + 1024), dim3(256), 0, stream,
                     q, k, v, Xs, Wq, Wk, Wv, Wo, Wt);
  hipLaunchKernelGGL(gemm_qkv, dim3(8, 32, 3), dim3(256), 0, stream,
                     Xs, Wt, Qb, Vt, bq, bk, bv);
  hipLaunchKernelGGL(attn_v9, dim3(Bb * Hh * (Ss / 16)), dim3(256), 0, stream,
                     Qb, Kb, Vt, attn, XsAO);
  hipLaunchKernelGGL(gemm_out, dim3(8, 64, 1), dim3(256), 0, stream,
                     XsAO, Wt + 3 * WT_SLAB, out, bo);
}